// Round 1
// baseline (1173.484 us; speedup 1.0000x reference)
//
#include <hip/hip_runtime.h>
#include <math.h>

// ---------------------------------------------------------------------------
// ResGatedGraphConv x2 + global_mean_pool + FC, fp32 throughout.
// CSR built on-device per call (ws is re-poisoned each launch).
// ---------------------------------------------------------------------------

#define C128 128

// ---------------- CSR build ----------------

__global__ __launch_bounds__(256) void hist_kernel(const int* __restrict__ dst,
                                                   int* __restrict__ cnt, int E) {
  int e = blockIdx.x * 256 + threadIdx.x;
  if (e < E) atomicAdd(&cnt[dst[e]], 1);
}

// per-512-chunk exclusive scan + chunk totals
__global__ __launch_bounds__(256) void scan1_kernel(const int* __restrict__ cnt,
                                                    int* __restrict__ tmp_excl,
                                                    int* __restrict__ bsum, int n) {
  __shared__ int s[256];
  int t = threadIdx.x;
  int base = blockIdx.x * 512;
  int i0 = base + 2 * t, i1 = i0 + 1;
  int a0 = (i0 < n) ? cnt[i0] : 0;
  int a1 = (i1 < n) ? cnt[i1] : 0;
  int sum = a0 + a1;
  s[t] = sum;
  __syncthreads();
  for (int off = 1; off < 256; off <<= 1) {
    int v = (t >= off) ? s[t - off] : 0;
    __syncthreads();
    s[t] += v;
    __syncthreads();
  }
  int excl = s[t] - sum;
  if (i0 < n) tmp_excl[i0] = excl;
  if (i1 < n) tmp_excl[i1] = excl + a0;
  if (t == 255) bsum[blockIdx.x] = s[255];
}

// single-block exclusive scan of chunk totals (nb <= 128)
__global__ __launch_bounds__(128) void scan2_kernel(const int* __restrict__ bsum,
                                                    int* __restrict__ boff, int nb) {
  __shared__ int s[128];
  int t = threadIdx.x;
  int v = (t < nb) ? bsum[t] : 0;
  s[t] = v;
  __syncthreads();
  for (int off = 1; off < 128; off <<= 1) {
    int u = (t >= off) ? s[t - off] : 0;
    __syncthreads();
    s[t] += u;
    __syncthreads();
  }
  if (t < nb) boff[t] = s[t] - v;
}

__global__ __launch_bounds__(256) void finalize_rp_kernel(const int* __restrict__ tmp_excl,
                                                          const int* __restrict__ boff,
                                                          int* __restrict__ row_ptr,
                                                          int* __restrict__ cursor,
                                                          int n, int E) {
  int i = blockIdx.x * 256 + threadIdx.x;
  if (i < n) {
    int v = tmp_excl[i] + boff[i >> 9];
    row_ptr[i] = v;
    cursor[i] = v;
  }
  if (i == 0) row_ptr[n] = E;
}

__global__ __launch_bounds__(256) void scatter_kernel(const int* __restrict__ src,
                                                      const int* __restrict__ dst,
                                                      int* __restrict__ cursor,
                                                      int* __restrict__ es, int E) {
  int e = blockIdx.x * 256 + threadIdx.x;
  if (e < E) {
    int i = dst[e];
    int p = atomicAdd(&cursor[i], 1);
    es[p] = src[e];
  }
}

// ---------------- fused 4-way GEMM:  Out_sel = X @ W_sel + bias_sel (+bias2) --

// block: 256 threads, tile 64 rows x 128 cols, grid.y selects which matrix
__global__ __launch_bounds__(256) void gemm4_kernel(
    const float* __restrict__ X,
    const float* __restrict__ W0, const float* __restrict__ W1,
    const float* __restrict__ W2, const float* __restrict__ W3,
    const float* __restrict__ bi0, const float* __restrict__ bi1,
    const float* __restrict__ bi2, const float* __restrict__ bi3,
    const float* __restrict__ bias2,  // extra bias, applied to sel==3 only
    float* __restrict__ O0, float* __restrict__ O1,
    float* __restrict__ O2, float* __restrict__ O3, int n) {
  __shared__ float xT[128 * 65];  // transposed x tile, stride 65 (conflict-free)

  int sel = blockIdx.y;
  const float* W = (sel == 0) ? W0 : (sel == 1) ? W1 : (sel == 2) ? W2 : W3;
  const float* bias = (sel == 0) ? bi0 : (sel == 1) ? bi1 : (sel == 2) ? bi2 : bi3;
  float* Out = (sel == 0) ? O0 : (sel == 1) ? O1 : (sel == 2) ? O2 : O3;

  int t = threadIdx.x;
  int row0 = blockIdx.x * 64;

  // stage transposed X tile
  for (int idx = t; idx < 64 * 128; idx += 256) {
    int r = idx >> 7, k = idx & 127;
    int gr = row0 + r;
    xT[k * 65 + r] = (gr < n) ? X[gr * 128 + k] : 0.0f;
  }
  __syncthreads();

  int og = t & 31;   // column quad: cols og*4 .. og*4+3
  int rg = t >> 5;   // row group: rows rg*8 .. rg*8+7

  float acc[8][4];
#pragma unroll
  for (int rr = 0; rr < 8; ++rr)
#pragma unroll
    for (int cc = 0; cc < 4; ++cc) acc[rr][cc] = 0.0f;

  const float4* W4 = (const float4*)W;
#pragma unroll 4
  for (int k = 0; k < 128; ++k) {
    float4 w = W4[k * 32 + og];
    const float* xk = &xT[k * 65 + rg * 8];
#pragma unroll
    for (int rr = 0; rr < 8; ++rr) {
      float xv = xk[rr];
      acc[rr][0] += xv * w.x;
      acc[rr][1] += xv * w.y;
      acc[rr][2] += xv * w.z;
      acc[rr][3] += xv * w.w;
    }
  }

  float4 bb = ((const float4*)bias)[og];
  if (sel == 3 && bias2 != nullptr) {
    float4 b2 = ((const float4*)bias2)[og];
    bb.x += b2.x; bb.y += b2.y; bb.z += b2.z; bb.w += b2.w;
  }
  float4* Out4 = (float4*)Out;
#pragma unroll
  for (int rr = 0; rr < 8; ++rr) {
    int gr = row0 + rg * 8 + rr;
    if (gr < n) {
      float4 o;
      o.x = acc[rr][0] + bb.x;
      o.y = acc[rr][1] + bb.y;
      o.z = acc[rr][2] + bb.z;
      o.w = acc[rr][3] + bb.w;
      Out4[gr * 32 + og] = o;
    }
  }
}

// ---------------- edge aggregation + residual + relu ----------------
// h[i] = relu( S[i] + sum_{j in in(i)} sigmoid(K[i]+Q[j]) * V[j] )
// 128 threads per node (one channel each), 2 nodes per block.

__global__ __launch_bounds__(256) void edge_agg_kernel(
    const float* __restrict__ K, const float* __restrict__ Q,
    const float* __restrict__ V, const float* __restrict__ S,
    const int* __restrict__ row_ptr, const int* __restrict__ es,
    float* __restrict__ H, int n) {
  int node = blockIdx.x * 2 + (threadIdx.x >> 7);
  if (node >= n) return;
  int c = threadIdx.x & 127;

  float kc = K[node * C128 + c];
  float acc = S[node * C128 + c];
  int e0 = row_ptr[node], e1 = row_ptr[node + 1];
  for (int e = e0; e < e1; ++e) {
    int j = es[e];
    float q = Q[j * C128 + c];
    float v = V[j * C128 + c];
    acc += v / (1.0f + __expf(-(kc + q)));
  }
  H[node * C128 + c] = fmaxf(acc, 0.0f);
}

// ---------------- global mean pool ----------------

__global__ __launch_bounds__(256) void graph_cnt_kernel(const int* __restrict__ batch,
                                                        float* __restrict__ gcnt, int n) {
  int i = blockIdx.x * 256 + threadIdx.x;
  if (i < n) atomicAdd(&gcnt[batch[i]], 1.0f);
}

__global__ __launch_bounds__(256) void pool_sum_kernel(const float* __restrict__ H,
                                                       const int* __restrict__ batch,
                                                       float* __restrict__ pool, int n) {
  __shared__ float accs[2 * 64 * 128];  // 64 KB: one 64x128 accumulator per half-block
  int t = threadIdx.x;
  for (int i = t; i < 2 * 64 * 128; i += 256) accs[i] = 0.0f;
  __syncthreads();

  int chunk = (n + gridDim.x - 1) / gridDim.x;
  int base = blockIdx.x * chunk;
  int end = base + chunk;
  if (end > n) end = n;
  int half = t >> 7, c = t & 127;

  for (int nb = base + half; nb < end; nb += 2) {
    int g = batch[nb];
    accs[half * 8192 + g * 128 + c] += H[nb * 128 + c];
  }
  __syncthreads();
  for (int i = t; i < 8192; i += 256) {
    float v = accs[i] + accs[8192 + i];
    if (v != 0.0f) atomicAdd(&pool[i], v);
  }
}

// ---------------- final FC ----------------

__global__ __launch_bounds__(128) void fc_kernel(const float* __restrict__ pool,
                                                 const float* __restrict__ gcnt,
                                                 const float* __restrict__ fcW,
                                                 const float* __restrict__ fcb,
                                                 float* __restrict__ out) {
  __shared__ float p[128];
  int g = blockIdx.x;
  int t = threadIdx.x;
  float cnt = fmaxf(gcnt[g], 1.0f);
  p[t] = pool[g * 128 + t] / cnt;
  __syncthreads();
  if (t < 10) {
    float s = fcb[t];
    for (int c = 0; c < 128; ++c) s += p[c] * fcW[c * 10 + t];
    out[g * 10 + t] = s;
  }
}

// ---------------------------------------------------------------------------

extern "C" void kernel_launch(void* const* d_in, const int* in_sizes, int n_in,
                              void* d_out, int out_size, void* d_ws, size_t ws_size,
                              hipStream_t stream) {
  const float* x   = (const float*)d_in[0];
  const int* eidx  = (const int*)d_in[1];
  const int* batch = (const int*)d_in[2];
  const float* Wk1 = (const float*)d_in[3];  const float* bk1 = (const float*)d_in[4];
  const float* Wq1 = (const float*)d_in[5];  const float* bq1 = (const float*)d_in[6];
  const float* Wv1 = (const float*)d_in[7];  const float* bv1 = (const float*)d_in[8];
  const float* Ws1 = (const float*)d_in[9];  const float* bs1 = (const float*)d_in[10];
  const float* b1  = (const float*)d_in[11];
  const float* Wk2 = (const float*)d_in[12]; const float* bk2 = (const float*)d_in[13];
  const float* Wq2 = (const float*)d_in[14]; const float* bq2 = (const float*)d_in[15];
  const float* Wv2 = (const float*)d_in[16]; const float* bv2 = (const float*)d_in[17];
  const float* Ws2 = (const float*)d_in[18]; const float* bs2 = (const float*)d_in[19];
  const float* b2  = (const float*)d_in[20];
  const float* fcW = (const float*)d_in[21]; const float* fcb = (const float*)d_in[22];
  float* out = (float*)d_out;

  const int N = in_sizes[0] / 128;   // 50000
  const int E = in_sizes[1] / 2;     // 800000
  const int* src = eidx;
  const int* dst = eidx + E;

  // ---- workspace carve (all 256B-aligned) ----
  char* w = (char*)d_ws;
  size_t off = 0;
  auto carve = [&](size_t bytes) -> void* {
    void* p = w + off;
    off += (bytes + 255) & ~size_t(255);
    return p;
  };
  const size_t featB = (size_t)N * 128 * sizeof(float);
  float* K  = (float*)carve(featB);
  float* Q  = (float*)carve(featB);
  float* V  = (float*)carve(featB);
  float* S  = (float*)carve(featB);
  float* H  = (float*)carve(featB);
  int* cnt      = (int*)carve((size_t)N * 4);
  int* row_ptr  = (int*)carve((size_t)(N + 1) * 4);
  int* cursor   = (int*)carve((size_t)N * 4);
  int* tmp_excl = (int*)carve((size_t)N * 4);
  int* bsum     = (int*)carve(256 * 4);
  int* boff     = (int*)carve(256 * 4);
  int* es       = (int*)carve((size_t)E * 4);
  float* pool   = (float*)carve(64 * 128 * 4);
  float* gcnt   = (float*)carve(64 * 4);
  (void)ws_size; (void)n_in; (void)out_size;

  // ---- zero the accumulated buffers ----
  hipMemsetAsync(cnt, 0, (size_t)N * 4, stream);
  hipMemsetAsync(pool, 0, 64 * 128 * 4, stream);
  hipMemsetAsync(gcnt, 0, 64 * 4, stream);

  // ---- CSR build (dst-indexed) ----
  int nb512 = (N + 511) / 512;
  hist_kernel<<<(E + 255) / 256, 256, 0, stream>>>(dst, cnt, E);
  scan1_kernel<<<nb512, 256, 0, stream>>>(cnt, tmp_excl, bsum, N);
  scan2_kernel<<<1, 128, 0, stream>>>(bsum, boff, nb512);
  finalize_rp_kernel<<<(N + 255) / 256, 256, 0, stream>>>(tmp_excl, boff, row_ptr, cursor, N, E);
  scatter_kernel<<<(E + 255) / 256, 256, 0, stream>>>(src, dst, cursor, es, E);

  dim3 ggrid((N + 63) / 64, 4);

  // ---- layer 1 ----
  gemm4_kernel<<<ggrid, 256, 0, stream>>>(x, Wk1, Wq1, Wv1, Ws1,
                                          bk1, bq1, bv1, bs1, b1,
                                          K, Q, V, S, N);
  edge_agg_kernel<<<(N + 1) / 2, 256, 0, stream>>>(K, Q, V, S, row_ptr, es, H, N);

  // ---- layer 2 ----
  gemm4_kernel<<<ggrid, 256, 0, stream>>>(H, Wk2, Wq2, Wv2, Ws2,
                                          bk2, bq2, bv2, bs2, b2,
                                          K, Q, V, S, N);
  edge_agg_kernel<<<(N + 1) / 2, 256, 0, stream>>>(K, Q, V, S, row_ptr, es, H, N);

  // ---- pool + fc ----
  graph_cnt_kernel<<<(N + 255) / 256, 256, 0, stream>>>(batch, gcnt, N);
  pool_sum_kernel<<<64, 256, 0, stream>>>(H, batch, pool, N);
  fc_kernel<<<64, 128, 0, stream>>>(pool, gcnt, fcW, fcb, out);
}

// Round 2
// 760.056 us; speedup vs baseline: 1.5439x; 1.5439x over previous
//
#include <hip/hip_runtime.h>
#include <math.h>

// ---------------------------------------------------------------------------
// ResGatedGraphConv x2 + global_mean_pool + FC, fp32 throughout.
// CSR built on-device per call (ws is re-poisoned each launch).
// R1: graph counts via binary search on sorted batch (was: 300us float-atomic
//     hotspot); edge_agg one-node-per-wave with float2 lanes + 2-edge unroll.
// ---------------------------------------------------------------------------

#define C128 128

// ---------------- CSR build ----------------

__global__ __launch_bounds__(256) void hist_kernel(const int* __restrict__ dst,
                                                   int* __restrict__ cnt, int E) {
  int e = blockIdx.x * 256 + threadIdx.x;
  if (e < E) atomicAdd(&cnt[dst[e]], 1);
}

// per-512-chunk exclusive scan + chunk totals
__global__ __launch_bounds__(256) void scan1_kernel(const int* __restrict__ cnt,
                                                    int* __restrict__ tmp_excl,
                                                    int* __restrict__ bsum, int n) {
  __shared__ int s[256];
  int t = threadIdx.x;
  int base = blockIdx.x * 512;
  int i0 = base + 2 * t, i1 = i0 + 1;
  int a0 = (i0 < n) ? cnt[i0] : 0;
  int a1 = (i1 < n) ? cnt[i1] : 0;
  int sum = a0 + a1;
  s[t] = sum;
  __syncthreads();
  for (int off = 1; off < 256; off <<= 1) {
    int v = (t >= off) ? s[t - off] : 0;
    __syncthreads();
    s[t] += v;
    __syncthreads();
  }
  int excl = s[t] - sum;
  if (i0 < n) tmp_excl[i0] = excl;
  if (i1 < n) tmp_excl[i1] = excl + a0;
  if (t == 255) bsum[blockIdx.x] = s[255];
}

// single-block exclusive scan of chunk totals (nb <= 128)
__global__ __launch_bounds__(128) void scan2_kernel(const int* __restrict__ bsum,
                                                    int* __restrict__ boff, int nb) {
  __shared__ int s[128];
  int t = threadIdx.x;
  int v = (t < nb) ? bsum[t] : 0;
  s[t] = v;
  __syncthreads();
  for (int off = 1; off < 128; off <<= 1) {
    int u = (t >= off) ? s[t - off] : 0;
    __syncthreads();
    s[t] += u;
    __syncthreads();
  }
  if (t < nb) boff[t] = s[t] - v;
}

__global__ __launch_bounds__(256) void finalize_rp_kernel(const int* __restrict__ tmp_excl,
                                                          const int* __restrict__ boff,
                                                          int* __restrict__ row_ptr,
                                                          int* __restrict__ cursor,
                                                          int n, int E) {
  int i = blockIdx.x * 256 + threadIdx.x;
  if (i < n) {
    int v = tmp_excl[i] + boff[i >> 9];
    row_ptr[i] = v;
    cursor[i] = v;
  }
  if (i == 0) row_ptr[n] = E;
}

__global__ __launch_bounds__(256) void scatter_kernel(const int* __restrict__ src,
                                                      const int* __restrict__ dst,
                                                      int* __restrict__ cursor,
                                                      int* __restrict__ es, int E) {
  int e = blockIdx.x * 256 + threadIdx.x;
  if (e < E) {
    int i = dst[e];
    int p = atomicAdd(&cursor[i], 1);
    es[p] = src[e];
  }
}

// ---------------- fused 4-way GEMM:  Out_sel = X @ W_sel + bias_sel (+bias2) --

// block: 256 threads, tile 64 rows x 128 cols, grid.y selects which matrix
__global__ __launch_bounds__(256) void gemm4_kernel(
    const float* __restrict__ X,
    const float* __restrict__ W0, const float* __restrict__ W1,
    const float* __restrict__ W2, const float* __restrict__ W3,
    const float* __restrict__ bi0, const float* __restrict__ bi1,
    const float* __restrict__ bi2, const float* __restrict__ bi3,
    const float* __restrict__ bias2,  // extra bias, applied to sel==3 only
    float* __restrict__ O0, float* __restrict__ O1,
    float* __restrict__ O2, float* __restrict__ O3, int n) {
  __shared__ float xT[128 * 65];  // transposed x tile, stride 65 (conflict-free)

  int sel = blockIdx.y;
  const float* W = (sel == 0) ? W0 : (sel == 1) ? W1 : (sel == 2) ? W2 : W3;
  const float* bias = (sel == 0) ? bi0 : (sel == 1) ? bi1 : (sel == 2) ? bi2 : bi3;
  float* Out = (sel == 0) ? O0 : (sel == 1) ? O1 : (sel == 2) ? O2 : O3;

  int t = threadIdx.x;
  int row0 = blockIdx.x * 64;

  // stage transposed X tile
  for (int idx = t; idx < 64 * 128; idx += 256) {
    int r = idx >> 7, k = idx & 127;
    int gr = row0 + r;
    xT[k * 65 + r] = (gr < n) ? X[gr * 128 + k] : 0.0f;
  }
  __syncthreads();

  int og = t & 31;   // column quad: cols og*4 .. og*4+3
  int rg = t >> 5;   // row group: rows rg*8 .. rg*8+7

  float acc[8][4];
#pragma unroll
  for (int rr = 0; rr < 8; ++rr)
#pragma unroll
    for (int cc = 0; cc < 4; ++cc) acc[rr][cc] = 0.0f;

  const float4* W4 = (const float4*)W;
#pragma unroll 4
  for (int k = 0; k < 128; ++k) {
    float4 w = W4[k * 32 + og];
    const float* xk = &xT[k * 65 + rg * 8];
#pragma unroll
    for (int rr = 0; rr < 8; ++rr) {
      float xv = xk[rr];
      acc[rr][0] += xv * w.x;
      acc[rr][1] += xv * w.y;
      acc[rr][2] += xv * w.z;
      acc[rr][3] += xv * w.w;
    }
  }

  float4 bb = ((const float4*)bias)[og];
  if (sel == 3 && bias2 != nullptr) {
    float4 b2 = ((const float4*)bias2)[og];
    bb.x += b2.x; bb.y += b2.y; bb.z += b2.z; bb.w += b2.w;
  }
  float4* Out4 = (float4*)Out;
#pragma unroll
  for (int rr = 0; rr < 8; ++rr) {
    int gr = row0 + rg * 8 + rr;
    if (gr < n) {
      float4 o;
      o.x = acc[rr][0] + bb.x;
      o.y = acc[rr][1] + bb.y;
      o.z = acc[rr][2] + bb.z;
      o.w = acc[rr][3] + bb.w;
      Out4[gr * 32 + og] = o;
    }
  }
}

// ---------------- edge aggregation + residual + relu ----------------
// h[i] = relu( S[i] + sum_{j in in(i)} sigmoid(K[i]+Q[j]) * V[j] )
// One node per wave: 64 lanes x float2 = 128 channels. 4 nodes per block.

__global__ __launch_bounds__(256) void edge_agg_kernel(
    const float* __restrict__ K, const float* __restrict__ Q,
    const float* __restrict__ V, const float* __restrict__ S,
    const int* __restrict__ row_ptr, const int* __restrict__ es,
    float* __restrict__ H, int n) {
  int wave = threadIdx.x >> 6;
  int lane = threadIdx.x & 63;
  int node = blockIdx.x * 4 + wave;
  if (node >= n) return;

  const float2* Q2 = (const float2*)Q;
  const float2* V2 = (const float2*)V;
  float2 kc = ((const float2*)K)[node * 64 + lane];
  float2 acc = ((const float2*)S)[node * 64 + lane];

  int e0 = row_ptr[node], e1 = row_ptr[node + 1];
  int e = e0;
  for (; e + 2 <= e1; e += 2) {
    int j0 = es[e], j1 = es[e + 1];
    float2 q0 = Q2[j0 * 64 + lane];
    float2 v0 = V2[j0 * 64 + lane];
    float2 q1 = Q2[j1 * 64 + lane];
    float2 v1 = V2[j1 * 64 + lane];
    acc.x += v0.x / (1.0f + __expf(-(kc.x + q0.x)));
    acc.y += v0.y / (1.0f + __expf(-(kc.y + q0.y)));
    acc.x += v1.x / (1.0f + __expf(-(kc.x + q1.x)));
    acc.y += v1.y / (1.0f + __expf(-(kc.y + q1.y)));
  }
  if (e < e1) {
    int j0 = es[e];
    float2 q0 = Q2[j0 * 64 + lane];
    float2 v0 = V2[j0 * 64 + lane];
    acc.x += v0.x / (1.0f + __expf(-(kc.x + q0.x)));
    acc.y += v0.y / (1.0f + __expf(-(kc.y + q0.y)));
  }
  float2 o;
  o.x = fmaxf(acc.x, 0.0f);
  o.y = fmaxf(acc.y, 0.0f);
  ((float2*)H)[node * 64 + lane] = o;
}

// ---------------- per-graph node counts via binary search (batch sorted) ----

__global__ __launch_bounds__(64) void graph_bounds_kernel(const int* __restrict__ batch,
                                                          float* __restrict__ gcnt, int n) {
  int g = threadIdx.x;  // 0..63
  // lower_bound: first i with batch[i] >= key
  auto lb = [&](int key) {
    int lo = 0, hi = n;
    while (lo < hi) {
      int mid = (lo + hi) >> 1;
      if (batch[mid] < key) lo = mid + 1; else hi = mid;
    }
    return lo;
  };
  int s = lb(g);
  int e = lb(g + 1);
  gcnt[g] = (float)(e - s);
}

// ---------------- global mean pool ----------------

__global__ __launch_bounds__(256) void pool_sum_kernel(const float* __restrict__ H,
                                                       const int* __restrict__ batch,
                                                       float* __restrict__ pool, int n) {
  __shared__ float accs[2 * 64 * 128];  // 64 KB: one 64x128 accumulator per half-block
  int t = threadIdx.x;
  for (int i = t; i < 2 * 64 * 128; i += 256) accs[i] = 0.0f;
  __syncthreads();

  int chunk = (n + gridDim.x - 1) / gridDim.x;
  int base = blockIdx.x * chunk;
  int end = base + chunk;
  if (end > n) end = n;
  int half = t >> 7, c = t & 127;

  for (int nb = base + half; nb < end; nb += 2) {
    int g = batch[nb];
    accs[half * 8192 + g * 128 + c] += H[nb * 128 + c];
  }
  __syncthreads();
  for (int i = t; i < 8192; i += 256) {
    float v = accs[i] + accs[8192 + i];
    if (v != 0.0f) atomicAdd(&pool[i], v);
  }
}

// ---------------- final FC ----------------

__global__ __launch_bounds__(128) void fc_kernel(const float* __restrict__ pool,
                                                 const float* __restrict__ gcnt,
                                                 const float* __restrict__ fcW,
                                                 const float* __restrict__ fcb,
                                                 float* __restrict__ out) {
  __shared__ float p[128];
  int g = blockIdx.x;
  int t = threadIdx.x;
  float cnt = fmaxf(gcnt[g], 1.0f);
  p[t] = pool[g * 128 + t] / cnt;
  __syncthreads();
  if (t < 10) {
    float s = fcb[t];
    for (int c = 0; c < 128; ++c) s += p[c] * fcW[c * 10 + t];
    out[g * 10 + t] = s;
  }
}

// ---------------------------------------------------------------------------

extern "C" void kernel_launch(void* const* d_in, const int* in_sizes, int n_in,
                              void* d_out, int out_size, void* d_ws, size_t ws_size,
                              hipStream_t stream) {
  const float* x   = (const float*)d_in[0];
  const int* eidx  = (const int*)d_in[1];
  const int* batch = (const int*)d_in[2];
  const float* Wk1 = (const float*)d_in[3];  const float* bk1 = (const float*)d_in[4];
  const float* Wq1 = (const float*)d_in[5];  const float* bq1 = (const float*)d_in[6];
  const float* Wv1 = (const float*)d_in[7];  const float* bv1 = (const float*)d_in[8];
  const float* Ws1 = (const float*)d_in[9];  const float* bs1 = (const float*)d_in[10];
  const float* b1  = (const float*)d_in[11];
  const float* Wk2 = (const float*)d_in[12]; const float* bk2 = (const float*)d_in[13];
  const float* Wq2 = (const float*)d_in[14]; const float* bq2 = (const float*)d_in[15];
  const float* Wv2 = (const float*)d_in[16]; const float* bv2 = (const float*)d_in[17];
  const float* Ws2 = (const float*)d_in[18]; const float* bs2 = (const float*)d_in[19];
  const float* b2  = (const float*)d_in[20];
  const float* fcW = (const float*)d_in[21]; const float* fcb = (const float*)d_in[22];
  float* out = (float*)d_out;

  const int N = in_sizes[0] / 128;   // 50000
  const int E = in_sizes[1] / 2;     // 800000
  const int* src = eidx;
  const int* dst = eidx + E;

  // ---- workspace carve (all 256B-aligned) ----
  char* w = (char*)d_ws;
  size_t off = 0;
  auto carve = [&](size_t bytes) -> void* {
    void* p = w + off;
    off += (bytes + 255) & ~size_t(255);
    return p;
  };
  const size_t featB = (size_t)N * 128 * sizeof(float);
  float* K  = (float*)carve(featB);
  float* Q  = (float*)carve(featB);
  float* V  = (float*)carve(featB);
  float* S  = (float*)carve(featB);
  float* H  = (float*)carve(featB);
  int* cnt      = (int*)carve((size_t)N * 4);
  int* row_ptr  = (int*)carve((size_t)(N + 1) * 4);
  int* cursor   = (int*)carve((size_t)N * 4);
  int* tmp_excl = (int*)carve((size_t)N * 4);
  int* bsum     = (int*)carve(256 * 4);
  int* boff     = (int*)carve(256 * 4);
  int* es       = (int*)carve((size_t)E * 4);
  float* pool   = (float*)carve(64 * 128 * 4);
  float* gcnt   = (float*)carve(64 * 4);
  (void)ws_size; (void)n_in; (void)out_size;

  // ---- zero the accumulated buffers ----
  hipMemsetAsync(cnt, 0, (size_t)N * 4, stream);
  hipMemsetAsync(pool, 0, 64 * 128 * 4, stream);

  // ---- CSR build (dst-indexed) ----
  int nb512 = (N + 511) / 512;
  hist_kernel<<<(E + 255) / 256, 256, 0, stream>>>(dst, cnt, E);
  scan1_kernel<<<nb512, 256, 0, stream>>>(cnt, tmp_excl, bsum, N);
  scan2_kernel<<<1, 128, 0, stream>>>(bsum, boff, nb512);
  finalize_rp_kernel<<<(N + 255) / 256, 256, 0, stream>>>(tmp_excl, boff, row_ptr, cursor, N, E);
  scatter_kernel<<<(E + 255) / 256, 256, 0, stream>>>(src, dst, cursor, es, E);

  dim3 ggrid((N + 63) / 64, 4);

  // ---- layer 1 ----
  gemm4_kernel<<<ggrid, 256, 0, stream>>>(x, Wk1, Wq1, Wv1, Ws1,
                                          bk1, bq1, bv1, bs1, b1,
                                          K, Q, V, S, N);
  edge_agg_kernel<<<(N + 3) / 4, 256, 0, stream>>>(K, Q, V, S, row_ptr, es, H, N);

  // ---- layer 2 ----
  gemm4_kernel<<<ggrid, 256, 0, stream>>>(H, Wk2, Wq2, Wv2, Ws2,
                                          bk2, bq2, bv2, bs2, b2,
                                          K, Q, V, S, N);
  edge_agg_kernel<<<(N + 3) / 4, 256, 0, stream>>>(K, Q, V, S, row_ptr, es, H, N);

  // ---- pool + fc ----
  graph_bounds_kernel<<<1, 64, 0, stream>>>(batch, gcnt, N);
  pool_sum_kernel<<<64, 256, 0, stream>>>(H, batch, pool, N);
  fc_kernel<<<64, 128, 0, stream>>>(pool, gcnt, fcW, fcb, out);
}

// Round 3
// 542.582 us; speedup vs baseline: 2.1628x; 1.4008x over previous
//
#include <hip/hip_runtime.h>
#include <math.h>

// ---------------------------------------------------------------------------
// ResGatedGraphConv x2 + global_mean_pool + FC.
// R2: GEMMs via bf16 MFMA (16x16x32), K/Q/V stored bf16 (S fp32 for residual),
//     edge_agg gathers bf16 (halved bytes, L2-resident), atomic-free pool.
// ---------------------------------------------------------------------------

typedef __attribute__((ext_vector_type(8))) short short8;
typedef __attribute__((ext_vector_type(4))) float floatx4;
typedef __attribute__((ext_vector_type(8))) unsigned short ushort8v;

__device__ __forceinline__ unsigned short f2b(float f) {
  unsigned int u = __builtin_bit_cast(unsigned int, f);
  u += 0x7fff + ((u >> 16) & 1);   // RNE
  return (unsigned short)(u >> 16);
}
__device__ __forceinline__ float b2f(unsigned short u) {
  return __builtin_bit_cast(float, ((unsigned int)u) << 16);
}

// ---------------- CSR build ----------------

__global__ __launch_bounds__(256) void hist_kernel(const int* __restrict__ dst,
                                                   int* __restrict__ cnt, int E) {
  int e = blockIdx.x * 256 + threadIdx.x;
  if (e < E) atomicAdd(&cnt[dst[e]], 1);
}

__global__ __launch_bounds__(256) void scan1_kernel(const int* __restrict__ cnt,
                                                    int* __restrict__ tmp_excl,
                                                    int* __restrict__ bsum, int n) {
  __shared__ int s[256];
  int t = threadIdx.x;
  int base = blockIdx.x * 512;
  int i0 = base + 2 * t, i1 = i0 + 1;
  int a0 = (i0 < n) ? cnt[i0] : 0;
  int a1 = (i1 < n) ? cnt[i1] : 0;
  int sum = a0 + a1;
  s[t] = sum;
  __syncthreads();
  for (int off = 1; off < 256; off <<= 1) {
    int v = (t >= off) ? s[t - off] : 0;
    __syncthreads();
    s[t] += v;
    __syncthreads();
  }
  int excl = s[t] - sum;
  if (i0 < n) tmp_excl[i0] = excl;
  if (i1 < n) tmp_excl[i1] = excl + a0;
  if (t == 255) bsum[blockIdx.x] = s[255];
}

__global__ __launch_bounds__(128) void scan2_kernel(const int* __restrict__ bsum,
                                                    int* __restrict__ boff, int nb) {
  __shared__ int s[128];
  int t = threadIdx.x;
  int v = (t < nb) ? bsum[t] : 0;
  s[t] = v;
  __syncthreads();
  for (int off = 1; off < 128; off <<= 1) {
    int u = (t >= off) ? s[t - off] : 0;
    __syncthreads();
    s[t] += u;
    __syncthreads();
  }
  if (t < nb) boff[t] = s[t] - v;
}

__global__ __launch_bounds__(256) void finalize_rp_kernel(const int* __restrict__ tmp_excl,
                                                          const int* __restrict__ boff,
                                                          int* __restrict__ row_ptr,
                                                          int* __restrict__ cursor,
                                                          int n, int E) {
  int i = blockIdx.x * 256 + threadIdx.x;
  if (i < n) {
    int v = tmp_excl[i] + boff[i >> 9];
    row_ptr[i] = v;
    cursor[i] = v;
  }
  if (i == 0) row_ptr[n] = E;
}

__global__ __launch_bounds__(256) void scatter_kernel(const int* __restrict__ src,
                                                      const int* __restrict__ dst,
                                                      int* __restrict__ cursor,
                                                      int* __restrict__ es, int E) {
  int e = blockIdx.x * 256 + threadIdx.x;
  if (e < E) {
    int i = dst[e];
    int p = atomicAdd(&cursor[i], 1);
    es[p] = src[e];
  }
}

// ---------------- dtype prep ----------------

// fp32 -> bf16, 4 elems/thread
__global__ __launch_bounds__(256) void convert_kernel(const float* __restrict__ X,
                                                      unsigned short* __restrict__ Xb,
                                                      int total4) {
  int i = blockIdx.x * 256 + threadIdx.x;
  if (i < total4) {
    float4 v = ((const float4*)X)[i];
    ushort4 o;
    o.x = f2b(v.x); o.y = f2b(v.y); o.z = f2b(v.z); o.w = f2b(v.w);
    ((ushort4*)Xb)[i] = o;
  }
}

// pack 8 weight matrices [k][n] fp32 -> WT [layer][mat][n][k] bf16
__global__ __launch_bounds__(256) void prepack_w_kernel(
    const float* __restrict__ Wk1, const float* __restrict__ Wq1,
    const float* __restrict__ Wv1, const float* __restrict__ Ws1,
    const float* __restrict__ Wk2, const float* __restrict__ Wq2,
    const float* __restrict__ Wv2, const float* __restrict__ Ws2,
    unsigned short* __restrict__ WT) {
  int idx = blockIdx.x * 256 + threadIdx.x;   // 0 .. 131071
  int layer = idx >> 16;
  int rem = idx & 0xFFFF;
  int mat = rem >> 14;
  int nk = rem & 0x3FFF;
  int nn = nk >> 7, kk = nk & 127;
  int sel = layer * 4 + mat;
  const float* W = (sel == 0) ? Wk1 : (sel == 1) ? Wq1 : (sel == 2) ? Wv1 :
                   (sel == 3) ? Ws1 : (sel == 4) ? Wk2 : (sel == 5) ? Wq2 :
                   (sel == 6) ? Wv2 : Ws2;
  WT[idx] = f2b(W[kk * 128 + nn]);
}

__global__ __launch_bounds__(256) void prepack_b_kernel(
    const float* __restrict__ bk1, const float* __restrict__ bq1,
    const float* __restrict__ bv1, const float* __restrict__ bs1,
    const float* __restrict__ b1,
    const float* __restrict__ bk2, const float* __restrict__ bq2,
    const float* __restrict__ bv2, const float* __restrict__ bs2,
    const float* __restrict__ b2,
    float* __restrict__ bcat) {
  int idx = blockIdx.x * 256 + threadIdx.x;   // 0 .. 1023
  if (idx >= 1024) return;
  int layer = idx >> 9;
  int rem = idx & 511;
  int mat = rem >> 7, c = rem & 127;
  int sel = layer * 4 + mat;
  const float* b = (sel == 0) ? bk1 : (sel == 1) ? bq1 : (sel == 2) ? bv1 :
                   (sel == 3) ? bs1 : (sel == 4) ? bk2 : (sel == 5) ? bq2 :
                   (sel == 6) ? bv2 : bs2;
  float v = b[c];
  if (mat == 3) v += (layer == 0) ? b1[c] : b2[c];
  bcat[idx] = v;
}

// ---------------- MFMA GEMM: [n x 128] bf16 @ WT[mat] -> K/Q/V (bf16), S (f32)

// block 256 thr = 4 waves (2x2 over 128x128 tile); blockIdx.y = matrix 0..3.
// K=128 entirely in one LDS tile; B-fragments straight from global (L1-hot).
__global__ __launch_bounds__(256) void gemm_mfma_kernel(
    const unsigned short* __restrict__ Xb,   // [n][128] bf16
    const unsigned short* __restrict__ WT,   // [4][128 n][128 k] bf16
    const float* __restrict__ bcat,          // [4][128]
    unsigned short* __restrict__ Kb, unsigned short* __restrict__ Qb,
    unsigned short* __restrict__ Vb, float* __restrict__ S, int n) {
  __shared__ unsigned short aT[128 * 136];       // +8 pad: 2-way banks only
  __shared__ float estage[4][16 * 68];           // per-wave epilogue strip

  int t = threadIdx.x;
  int row0 = blockIdx.x * 128;
  int m = blockIdx.y;

  // stage A tile (zero-fill past n)
#pragma unroll
  for (int i = 0; i < 8; ++i) {
    int c = i * 256 + t;          // 16B chunk id, 0..2047
    int r = c >> 4, col16 = c & 15;
    int4 v = make_int4(0, 0, 0, 0);
    if (row0 + r < n) v = *(const int4*)&Xb[(size_t)(row0 + r) * 128 + col16 * 8];
    *(int4*)&aT[r * 136 + col16 * 8] = v;
  }
  __syncthreads();

  int lane = t & 63, wid = t >> 6;
  int wy = wid >> 1, wx = wid & 1;
  int l15 = lane & 15, lq = lane >> 4;

  const unsigned short* WTm = WT + (size_t)m * 16384;

  floatx4 acc[4][4];
#pragma unroll
  for (int mf = 0; mf < 4; ++mf)
#pragma unroll
    for (int nf = 0; nf < 4; ++nf) acc[mf][nf] = (floatx4)(0.0f);

#pragma unroll
  for (int ks = 0; ks < 4; ++ks) {
    int kof = ks * 32 + lq * 8;
    short8 a[4], b[4];
#pragma unroll
    for (int mf = 0; mf < 4; ++mf)
      a[mf] = *(const short8*)&aT[(wy * 64 + mf * 16 + l15) * 136 + kof];
#pragma unroll
    for (int nf = 0; nf < 4; ++nf)
      b[nf] = *(const short8*)&WTm[(size_t)(wx * 64 + nf * 16 + l15) * 128 + kof];
#pragma unroll
    for (int mf = 0; mf < 4; ++mf)
#pragma unroll
      for (int nf = 0; nf < 4; ++nf)
        acc[mf][nf] = __builtin_amdgcn_mfma_f32_16x16x32_bf16(a[mf], b[nf], acc[mf][nf], 0, 0, 0);
  }

  // epilogue: LDS transpose to coalesced row-major stores + bias
  const float* bias = bcat + m * 128;
  int r4 = lane >> 2, cq4 = lane & 3;
  int col = wx * 64 + cq4 * 16;      // within the 128-ch output row
  float4 bv[4];
#pragma unroll
  for (int j = 0; j < 4; ++j) bv[j] = *(const float4*)&bias[col + j * 4];

  unsigned short* Ob = (m == 0) ? Kb : (m == 1) ? Qb : Vb;

#pragma unroll
  for (int mf = 0; mf < 4; ++mf) {
#pragma unroll
    for (int nf = 0; nf < 4; ++nf)
#pragma unroll
      for (int i = 0; i < 4; ++i)
        estage[wid][(lq * 4 + i) * 68 + nf * 16 + l15] = acc[mf][nf][i];
    // per-wave region, wave-lockstep: no barrier needed
    int grow = row0 + wy * 64 + mf * 16 + r4;
    if (grow < n) {
      float4 p[4];
#pragma unroll
      for (int j = 0; j < 4; ++j) {
        float4 e = *(const float4*)&estage[wid][r4 * 68 + cq4 * 16 + j * 4];
        p[j].x = e.x + bv[j].x; p[j].y = e.y + bv[j].y;
        p[j].z = e.z + bv[j].z; p[j].w = e.w + bv[j].w;
      }
      if (m < 3) {
        ushort8v o0, o1;
        o0[0] = f2b(p[0].x); o0[1] = f2b(p[0].y); o0[2] = f2b(p[0].z); o0[3] = f2b(p[0].w);
        o0[4] = f2b(p[1].x); o0[5] = f2b(p[1].y); o0[6] = f2b(p[1].z); o0[7] = f2b(p[1].w);
        o1[0] = f2b(p[2].x); o1[1] = f2b(p[2].y); o1[2] = f2b(p[2].z); o1[3] = f2b(p[2].w);
        o1[4] = f2b(p[3].x); o1[5] = f2b(p[3].y); o1[6] = f2b(p[3].z); o1[7] = f2b(p[3].w);
        *(ushort8v*)&Ob[(size_t)grow * 128 + col] = o0;
        *(ushort8v*)&Ob[(size_t)grow * 128 + col + 8] = o1;
      } else {
#pragma unroll
        for (int j = 0; j < 4; ++j)
          *(float4*)&S[(size_t)grow * 128 + col + j * 4] = p[j];
      }
    }
  }
}

// ---------------- edge aggregation + residual + relu ----------------
// h[i] = relu( S[i] + sum_j sigmoid(K[i]+Q[j]) * V[j] ), K/Q/V bf16, S f32.
// One node per wave; 32 lanes x 4ch per edge-row; 2 edges per iteration.

__global__ __launch_bounds__(256) void edge_agg_kernel(
    const unsigned short* __restrict__ Kb, const unsigned short* __restrict__ Qb,
    const unsigned short* __restrict__ Vb, const float* __restrict__ S,
    const int* __restrict__ row_ptr, const int* __restrict__ es,
    unsigned short* __restrict__ Hb, float* __restrict__ Hf, int mode, int n) {
  int wid = threadIdx.x >> 6;
  int lane = threadIdx.x & 63;
  int node = blockIdx.x * 4 + wid;
  if (node >= n) return;
  int cq = lane & 31;     // channel quad: ch 4*cq..4*cq+3
  int half = lane >> 5;

  ushort4 kr = ((const ushort4*)Kb)[node * 32 + cq];
  float4 kc;
  kc.x = b2f(kr.x); kc.y = b2f(kr.y); kc.z = b2f(kr.z); kc.w = b2f(kr.w);

  float4 acc;
  if (half == 0) acc = ((const float4*)S)[node * 32 + cq];
  else { acc.x = 0.f; acc.y = 0.f; acc.z = 0.f; acc.w = 0.f; }

  int e0 = row_ptr[node], e1 = row_ptr[node + 1];
  for (int e = e0 + half; e < e1; e += 2) {
    int j = es[e];
    ushort4 qr = ((const ushort4*)Qb)[j * 32 + cq];
    ushort4 vr = ((const ushort4*)Vb)[j * 32 + cq];
    float qx = b2f(qr.x), qy = b2f(qr.y), qz = b2f(qr.z), qw = b2f(qr.w);
    float vx = b2f(vr.x), vy = b2f(vr.y), vz = b2f(vr.z), vw = b2f(vr.w);
    acc.x += vx / (1.0f + __expf(-(kc.x + qx)));
    acc.y += vy / (1.0f + __expf(-(kc.y + qy)));
    acc.z += vz / (1.0f + __expf(-(kc.z + qz)));
    acc.w += vw / (1.0f + __expf(-(kc.w + qw)));
  }
  // combine halves
  acc.x += __shfl_down(acc.x, 32);
  acc.y += __shfl_down(acc.y, 32);
  acc.z += __shfl_down(acc.z, 32);
  acc.w += __shfl_down(acc.w, 32);
  if (half == 0) {
    acc.x = fmaxf(acc.x, 0.f); acc.y = fmaxf(acc.y, 0.f);
    acc.z = fmaxf(acc.z, 0.f); acc.w = fmaxf(acc.w, 0.f);
    if (mode == 0) {
      ushort4 o;
      o.x = f2b(acc.x); o.y = f2b(acc.y); o.z = f2b(acc.z); o.w = f2b(acc.w);
      ((ushort4*)Hb)[node * 32 + cq] = o;
    } else {
      ((float4*)Hf)[node * 32 + cq] = acc;
    }
  }
}

// ---------------- graph bounds + mean pool + FC ----------------

__global__ __launch_bounds__(64) void graph_bounds_kernel(const int* __restrict__ batch,
                                                          int* __restrict__ gstart, int n) {
  int g = threadIdx.x;  // 0..63
  int lo = 0, hi = n;
  while (lo < hi) {
    int mid = (lo + hi) >> 1;
    if (batch[mid] < g) lo = mid + 1; else hi = mid;
  }
  gstart[g] = lo;
  if (g == 63) gstart[64] = n;
}

__global__ __launch_bounds__(256) void pool_mean_kernel(const float* __restrict__ Hf,
                                                        const int* __restrict__ gstart,
                                                        float* __restrict__ pool) {
  __shared__ float red[128];
  int g = blockIdx.x;
  int t = threadIdx.x;
  int c = t & 127, half = t >> 7;
  int s = gstart[g], e = gstart[g + 1];
  float acc = 0.0f;
  for (int nd = s + half; nd < e; nd += 2) acc += Hf[(size_t)nd * 128 + c];
  if (half) red[c] = acc;
  __syncthreads();
  if (!half) {
    float tot = acc + red[c];
    pool[g * 128 + c] = (e > s) ? tot / (float)(e - s) : 0.0f;
  }
}

__global__ __launch_bounds__(128) void fc_kernel(const float* __restrict__ pool,
                                                 const float* __restrict__ fcW,
                                                 const float* __restrict__ fcb,
                                                 float* __restrict__ out) {
  __shared__ float p[128];
  int g = blockIdx.x;
  int t = threadIdx.x;
  p[t] = pool[g * 128 + t];
  __syncthreads();
  if (t < 10) {
    float s = fcb[t];
    for (int c = 0; c < 128; ++c) s += p[c] * fcW[c * 10 + t];
    out[g * 10 + t] = s;
  }
}

// ---------------------------------------------------------------------------

extern "C" void kernel_launch(void* const* d_in, const int* in_sizes, int n_in,
                              void* d_out, int out_size, void* d_ws, size_t ws_size,
                              hipStream_t stream) {
  const float* x   = (const float*)d_in[0];
  const int* eidx  = (const int*)d_in[1];
  const int* batch = (const int*)d_in[2];
  const float* Wk1 = (const float*)d_in[3];  const float* bk1 = (const float*)d_in[4];
  const float* Wq1 = (const float*)d_in[5];  const float* bq1 = (const float*)d_in[6];
  const float* Wv1 = (const float*)d_in[7];  const float* bv1 = (const float*)d_in[8];
  const float* Ws1 = (const float*)d_in[9];  const float* bs1 = (const float*)d_in[10];
  const float* b1  = (const float*)d_in[11];
  const float* Wk2 = (const float*)d_in[12]; const float* bk2 = (const float*)d_in[13];
  const float* Wq2 = (const float*)d_in[14]; const float* bq2 = (const float*)d_in[15];
  const float* Wv2 = (const float*)d_in[16]; const float* bv2 = (const float*)d_in[17];
  const float* Ws2 = (const float*)d_in[18]; const float* bs2 = (const float*)d_in[19];
  const float* b2  = (const float*)d_in[20];
  const float* fcW = (const float*)d_in[21]; const float* fcb = (const float*)d_in[22];
  float* out = (float*)d_out;

  const int N = in_sizes[0] / 128;   // 50000
  const int E = in_sizes[1] / 2;     // 800000
  const int* src = eidx;
  const int* dst = eidx + E;

  // ---- workspace carve ----
  char* w = (char*)d_ws;
  size_t off = 0;
  auto carve = [&](size_t bytes) -> void* {
    void* p = w + off;
    off += (bytes + 255) & ~size_t(255);
    return p;
  };
  const size_t featB16 = (size_t)N * 128 * 2;
  const size_t featB32 = (size_t)N * 128 * 4;
  unsigned short* Xb = (unsigned short*)carve(featB16);
  unsigned short* Kb = (unsigned short*)carve(featB16);
  unsigned short* Qb = (unsigned short*)carve(featB16);
  unsigned short* Vb = (unsigned short*)carve(featB16);
  unsigned short* Hb = (unsigned short*)carve(featB16);
  float* S  = (float*)carve(featB32);
  float* Hf = (float*)carve(featB32);
  unsigned short* WT = (unsigned short*)carve(2 * 4 * 128 * 128 * 2);
  float* bcat = (float*)carve(1024 * 4);
  int* cnt      = (int*)carve((size_t)N * 4);
  int* row_ptr  = (int*)carve((size_t)(N + 1) * 4);
  int* cursor   = (int*)carve((size_t)N * 4);
  int* tmp_excl = (int*)carve((size_t)N * 4);
  int* bsum     = (int*)carve(256 * 4);
  int* boff     = (int*)carve(256 * 4);
  int* es       = (int*)carve((size_t)E * 4);
  int* gstart   = (int*)carve(65 * 4);
  float* pool   = (float*)carve(64 * 128 * 4);
  (void)ws_size; (void)n_in; (void)out_size;

  hipMemsetAsync(cnt, 0, (size_t)N * 4, stream);

  // ---- prep: CSR + dtype packing ----
  int nb512 = (N + 511) / 512;
  hist_kernel<<<(E + 255) / 256, 256, 0, stream>>>(dst, cnt, E);
  scan1_kernel<<<nb512, 256, 0, stream>>>(cnt, tmp_excl, bsum, N);
  scan2_kernel<<<1, 128, 0, stream>>>(bsum, boff, nb512);
  finalize_rp_kernel<<<(N + 255) / 256, 256, 0, stream>>>(tmp_excl, boff, row_ptr, cursor, N, E);
  scatter_kernel<<<(E + 255) / 256, 256, 0, stream>>>(src, dst, cursor, es, E);

  convert_kernel<<<(N * 32 + 255) / 256, 256, 0, stream>>>(x, Xb, N * 32);
  prepack_w_kernel<<<512, 256, 0, stream>>>(Wk1, Wq1, Wv1, Ws1, Wk2, Wq2, Wv2, Ws2, WT);
  prepack_b_kernel<<<4, 256, 0, stream>>>(bk1, bq1, bv1, bs1, b1,
                                          bk2, bq2, bv2, bs2, b2, bcat);

  dim3 ggrid((N + 127) / 128, 4);

  // ---- layer 1 ----
  gemm_mfma_kernel<<<ggrid, 256, 0, stream>>>(Xb, WT, bcat, Kb, Qb, Vb, S, N);
  edge_agg_kernel<<<(N + 3) / 4, 256, 0, stream>>>(Kb, Qb, Vb, S, row_ptr, es,
                                                   Hb, Hf, 0, N);

  // ---- layer 2 ----
  gemm_mfma_kernel<<<ggrid, 256, 0, stream>>>(Hb, WT + 65536, bcat + 512,
                                              Kb, Qb, Vb, S, N);
  edge_agg_kernel<<<(N + 3) / 4, 256, 0, stream>>>(Kb, Qb, Vb, S, row_ptr, es,
                                                   Hb, Hf, 1, N);

  // ---- pool + fc ----
  graph_bounds_kernel<<<1, 64, 0, stream>>>(batch, gstart, N);
  pool_mean_kernel<<<64, 256, 0, stream>>>(Hf, gstart, pool);
  fc_kernel<<<64, 128, 0, stream>>>(pool, fcW, fcb, out);
}

// Round 4
// 431.661 us; speedup vs baseline: 2.7185x; 1.2570x over previous
//
#include <hip/hip_runtime.h>
#include <math.h>

// ---------------------------------------------------------------------------
// ResGatedGraphConv x2 + global_mean_pool + FC.
// R2: GEMMs via bf16 MFMA; K/Q/V bf16; S fp32.
// R3: pool split 16 blocks/graph + atomics (was 64-block latency hole);
//     edge_agg 4 edges/wave (ushort8 lanes) + es software pipeline.
// ---------------------------------------------------------------------------

typedef __attribute__((ext_vector_type(8))) short short8;
typedef __attribute__((ext_vector_type(4))) float floatx4;
typedef __attribute__((ext_vector_type(8))) float floatx8;
typedef __attribute__((ext_vector_type(8))) unsigned short ushort8v;

__device__ __forceinline__ unsigned short f2b(float f) {
  unsigned int u = __builtin_bit_cast(unsigned int, f);
  u += 0x7fff + ((u >> 16) & 1);   // RNE
  return (unsigned short)(u >> 16);
}
__device__ __forceinline__ float b2f(unsigned short u) {
  return __builtin_bit_cast(float, ((unsigned int)u) << 16);
}

// ---------------- CSR build ----------------

__global__ __launch_bounds__(256) void hist_kernel(const int* __restrict__ dst,
                                                   int* __restrict__ cnt, int E) {
  int e = blockIdx.x * 256 + threadIdx.x;
  if (e < E) atomicAdd(&cnt[dst[e]], 1);
}

__global__ __launch_bounds__(256) void scan1_kernel(const int* __restrict__ cnt,
                                                    int* __restrict__ tmp_excl,
                                                    int* __restrict__ bsum, int n) {
  __shared__ int s[256];
  int t = threadIdx.x;
  int base = blockIdx.x * 512;
  int i0 = base + 2 * t, i1 = i0 + 1;
  int a0 = (i0 < n) ? cnt[i0] : 0;
  int a1 = (i1 < n) ? cnt[i1] : 0;
  int sum = a0 + a1;
  s[t] = sum;
  __syncthreads();
  for (int off = 1; off < 256; off <<= 1) {
    int v = (t >= off) ? s[t - off] : 0;
    __syncthreads();
    s[t] += v;
    __syncthreads();
  }
  int excl = s[t] - sum;
  if (i0 < n) tmp_excl[i0] = excl;
  if (i1 < n) tmp_excl[i1] = excl + a0;
  if (t == 255) bsum[blockIdx.x] = s[255];
}

__global__ __launch_bounds__(128) void scan2_kernel(const int* __restrict__ bsum,
                                                    int* __restrict__ boff, int nb) {
  __shared__ int s[128];
  int t = threadIdx.x;
  int v = (t < nb) ? bsum[t] : 0;
  s[t] = v;
  __syncthreads();
  for (int off = 1; off < 128; off <<= 1) {
    int u = (t >= off) ? s[t - off] : 0;
    __syncthreads();
    s[t] += u;
    __syncthreads();
  }
  if (t < nb) boff[t] = s[t] - v;
}

__global__ __launch_bounds__(256) void finalize_rp_kernel(const int* __restrict__ tmp_excl,
                                                          const int* __restrict__ boff,
                                                          int* __restrict__ row_ptr,
                                                          int* __restrict__ cursor,
                                                          int n, int E) {
  int i = blockIdx.x * 256 + threadIdx.x;
  if (i < n) {
    int v = tmp_excl[i] + boff[i >> 9];
    row_ptr[i] = v;
    cursor[i] = v;
  }
  if (i == 0) row_ptr[n] = E;
}

__global__ __launch_bounds__(256) void scatter_kernel(const int* __restrict__ src,
                                                      const int* __restrict__ dst,
                                                      int* __restrict__ cursor,
                                                      int* __restrict__ es, int E) {
  int e = blockIdx.x * 256 + threadIdx.x;
  if (e < E) {
    int i = dst[e];
    int p = atomicAdd(&cursor[i], 1);
    es[p] = src[e];
  }
}

// ---------------- dtype prep ----------------

__global__ __launch_bounds__(256) void convert_kernel(const float* __restrict__ X,
                                                      unsigned short* __restrict__ Xb,
                                                      int total4) {
  int i = blockIdx.x * 256 + threadIdx.x;
  if (i < total4) {
    float4 v = ((const float4*)X)[i];
    ushort4 o;
    o.x = f2b(v.x); o.y = f2b(v.y); o.z = f2b(v.z); o.w = f2b(v.w);
    ((ushort4*)Xb)[i] = o;
  }
}

// pack 8 weight matrices [k][n] fp32 -> WT [layer][mat][n][k] bf16
__global__ __launch_bounds__(256) void prepack_w_kernel(
    const float* __restrict__ Wk1, const float* __restrict__ Wq1,
    const float* __restrict__ Wv1, const float* __restrict__ Ws1,
    const float* __restrict__ Wk2, const float* __restrict__ Wq2,
    const float* __restrict__ Wv2, const float* __restrict__ Ws2,
    unsigned short* __restrict__ WT) {
  int idx = blockIdx.x * 256 + threadIdx.x;   // 0 .. 131071
  int layer = idx >> 16;
  int rem = idx & 0xFFFF;
  int mat = rem >> 14;
  int nk = rem & 0x3FFF;
  int nn = nk >> 7, kk = nk & 127;
  int sel = layer * 4 + mat;
  const float* W = (sel == 0) ? Wk1 : (sel == 1) ? Wq1 : (sel == 2) ? Wv1 :
                   (sel == 3) ? Ws1 : (sel == 4) ? Wk2 : (sel == 5) ? Wq2 :
                   (sel == 6) ? Wv2 : Ws2;
  WT[idx] = f2b(W[kk * 128 + nn]);
}

__global__ __launch_bounds__(256) void prepack_b_kernel(
    const float* __restrict__ bk1, const float* __restrict__ bq1,
    const float* __restrict__ bv1, const float* __restrict__ bs1,
    const float* __restrict__ b1,
    const float* __restrict__ bk2, const float* __restrict__ bq2,
    const float* __restrict__ bv2, const float* __restrict__ bs2,
    const float* __restrict__ b2,
    float* __restrict__ bcat) {
  int idx = blockIdx.x * 256 + threadIdx.x;   // 0 .. 1023
  if (idx >= 1024) return;
  int layer = idx >> 9;
  int rem = idx & 511;
  int mat = rem >> 7, c = rem & 127;
  int sel = layer * 4 + mat;
  const float* b = (sel == 0) ? bk1 : (sel == 1) ? bq1 : (sel == 2) ? bv1 :
                   (sel == 3) ? bs1 : (sel == 4) ? bk2 : (sel == 5) ? bq2 :
                   (sel == 6) ? bv2 : bs2;
  float v = b[c];
  if (mat == 3) v += (layer == 0) ? b1[c] : b2[c];
  bcat[idx] = v;
}

// ---------------- MFMA GEMM: [n x 128] bf16 @ WT[mat] -> K/Q/V (bf16), S (f32)

__global__ __launch_bounds__(256) void gemm_mfma_kernel(
    const unsigned short* __restrict__ Xb,   // [n][128] bf16
    const unsigned short* __restrict__ WT,   // [4][128 n][128 k] bf16
    const float* __restrict__ bcat,          // [4][128]
    unsigned short* __restrict__ Kb, unsigned short* __restrict__ Qb,
    unsigned short* __restrict__ Vb, float* __restrict__ S, int n) {
  __shared__ unsigned short aT[128 * 136];       // +8 pad: 2-way banks only
  __shared__ float estage[4][16 * 68];           // per-wave epilogue strip

  int t = threadIdx.x;
  int row0 = blockIdx.x * 128;
  int m = blockIdx.y;

#pragma unroll
  for (int i = 0; i < 8; ++i) {
    int c = i * 256 + t;          // 16B chunk id, 0..2047
    int r = c >> 4, col16 = c & 15;
    int4 v = make_int4(0, 0, 0, 0);
    if (row0 + r < n) v = *(const int4*)&Xb[(size_t)(row0 + r) * 128 + col16 * 8];
    *(int4*)&aT[r * 136 + col16 * 8] = v;
  }
  __syncthreads();

  int lane = t & 63, wid = t >> 6;
  int wy = wid >> 1, wx = wid & 1;
  int l15 = lane & 15, lq = lane >> 4;

  const unsigned short* WTm = WT + (size_t)m * 16384;

  floatx4 acc[4][4];
#pragma unroll
  for (int mf = 0; mf < 4; ++mf)
#pragma unroll
    for (int nf = 0; nf < 4; ++nf) acc[mf][nf] = (floatx4)(0.0f);

#pragma unroll
  for (int ks = 0; ks < 4; ++ks) {
    int kof = ks * 32 + lq * 8;
    short8 a[4], b[4];
#pragma unroll
    for (int mf = 0; mf < 4; ++mf)
      a[mf] = *(const short8*)&aT[(wy * 64 + mf * 16 + l15) * 136 + kof];
#pragma unroll
    for (int nf = 0; nf < 4; ++nf)
      b[nf] = *(const short8*)&WTm[(size_t)(wx * 64 + nf * 16 + l15) * 128 + kof];
#pragma unroll
    for (int mf = 0; mf < 4; ++mf)
#pragma unroll
      for (int nf = 0; nf < 4; ++nf)
        acc[mf][nf] = __builtin_amdgcn_mfma_f32_16x16x32_bf16(a[mf], b[nf], acc[mf][nf], 0, 0, 0);
  }

  const float* bias = bcat + m * 128;
  int r4 = lane >> 2, cq4 = lane & 3;
  int col = wx * 64 + cq4 * 16;
  float4 bv[4];
#pragma unroll
  for (int j = 0; j < 4; ++j) bv[j] = *(const float4*)&bias[col + j * 4];

  unsigned short* Ob = (m == 0) ? Kb : (m == 1) ? Qb : Vb;

#pragma unroll
  for (int mf = 0; mf < 4; ++mf) {
#pragma unroll
    for (int nf = 0; nf < 4; ++nf)
#pragma unroll
      for (int i = 0; i < 4; ++i)
        estage[wid][(lq * 4 + i) * 68 + nf * 16 + l15] = acc[mf][nf][i];
    int grow = row0 + wy * 64 + mf * 16 + r4;
    if (grow < n) {
      float4 p[4];
#pragma unroll
      for (int j = 0; j < 4; ++j) {
        float4 e = *(const float4*)&estage[wid][r4 * 68 + cq4 * 16 + j * 4];
        p[j].x = e.x + bv[j].x; p[j].y = e.y + bv[j].y;
        p[j].z = e.z + bv[j].z; p[j].w = e.w + bv[j].w;
      }
      if (m < 3) {
        ushort8v o0, o1;
        o0[0] = f2b(p[0].x); o0[1] = f2b(p[0].y); o0[2] = f2b(p[0].z); o0[3] = f2b(p[0].w);
        o0[4] = f2b(p[1].x); o0[5] = f2b(p[1].y); o0[6] = f2b(p[1].z); o0[7] = f2b(p[1].w);
        o1[0] = f2b(p[2].x); o1[1] = f2b(p[2].y); o1[2] = f2b(p[2].z); o1[3] = f2b(p[2].w);
        o1[4] = f2b(p[3].x); o1[5] = f2b(p[3].y); o1[6] = f2b(p[3].z); o1[7] = f2b(p[3].w);
        *(ushort8v*)&Ob[(size_t)grow * 128 + col] = o0;
        *(ushort8v*)&Ob[(size_t)grow * 128 + col + 8] = o1;
      } else {
#pragma unroll
        for (int j = 0; j < 4; ++j)
          *(float4*)&S[(size_t)grow * 128 + col + j * 4] = p[j];
      }
    }
  }
}

// ---------------- edge aggregation + residual + relu ----------------
// h[i] = relu( S[i] + sum_j sigmoid(K[i]+Q[j]) * V[j] )
// One node per wave; 4 edge slots (16 lanes x ushort8 = 256B row each);
// es software-pipelined; shfl_xor(16,32) combines slots.

__global__ __launch_bounds__(256) void edge_agg_kernel(
    const unsigned short* __restrict__ Kb, const unsigned short* __restrict__ Qb,
    const unsigned short* __restrict__ Vb, const float* __restrict__ S,
    const int* __restrict__ row_ptr, const int* __restrict__ es,
    unsigned short* __restrict__ Hb, float* __restrict__ Hf, int mode, int n) {
  int wid = threadIdx.x >> 6;
  int lane = threadIdx.x & 63;
  int node = blockIdx.x * 4 + wid;
  if (node >= n) return;
  int grp = lane >> 4;     // edge slot 0..3
  int l16 = lane & 15;     // channels l16*8 .. l16*8+7

  ushort8v kr = *(const ushort8v*)&Kb[(size_t)node * 128 + l16 * 8];
  float kc[8];
#pragma unroll
  for (int i = 0; i < 8; ++i) kc[i] = b2f(kr[i]);

  floatx8 acc = (floatx8)(0.0f);

  int e0 = row_ptr[node], e1 = row_ptr[node + 1];
  int e = e0 + grp;
  int j = (e < e1) ? es[e] : -1;
  while (j >= 0) {
    int en = e + 4;
    int jn = (en < e1) ? es[en] : -1;
    ushort8v q8 = *(const ushort8v*)&Qb[(size_t)j * 128 + l16 * 8];
    ushort8v v8 = *(const ushort8v*)&Vb[(size_t)j * 128 + l16 * 8];
#pragma unroll
    for (int i = 0; i < 8; ++i) {
      float q = b2f(q8[i]);
      float v = b2f(v8[i]);
      acc[i] += v / (1.0f + __expf(-(kc[i] + q)));
    }
    e = en; j = jn;
  }

  // combine 4 edge slots
#pragma unroll
  for (int i = 0; i < 8; ++i) {
    acc[i] += __shfl_xor(acc[i], 16);
    acc[i] += __shfl_xor(acc[i], 32);
  }

  if (grp == 0) {
    float4 s0 = *(const float4*)&S[(size_t)node * 128 + l16 * 8];
    float4 s1 = *(const float4*)&S[(size_t)node * 128 + l16 * 8 + 4];
    float r[8];
    r[0] = fmaxf(acc[0] + s0.x, 0.f); r[1] = fmaxf(acc[1] + s0.y, 0.f);
    r[2] = fmaxf(acc[2] + s0.z, 0.f); r[3] = fmaxf(acc[3] + s0.w, 0.f);
    r[4] = fmaxf(acc[4] + s1.x, 0.f); r[5] = fmaxf(acc[5] + s1.y, 0.f);
    r[6] = fmaxf(acc[6] + s1.z, 0.f); r[7] = fmaxf(acc[7] + s1.w, 0.f);
    if (mode == 0) {
      ushort8v o;
#pragma unroll
      for (int i = 0; i < 8; ++i) o[i] = f2b(r[i]);
      *(ushort8v*)&Hb[(size_t)node * 128 + l16 * 8] = o;
    } else {
      float4 h0 = make_float4(r[0], r[1], r[2], r[3]);
      float4 h1 = make_float4(r[4], r[5], r[6], r[7]);
      *(float4*)&Hf[(size_t)node * 128 + l16 * 8] = h0;
      *(float4*)&Hf[(size_t)node * 128 + l16 * 8 + 4] = h1;
    }
  }
}

// ---------------- graph bounds + mean pool + FC ----------------

__global__ __launch_bounds__(64) void graph_bounds_kernel(const int* __restrict__ batch,
                                                          int* __restrict__ gstart, int n) {
  int g = threadIdx.x;  // 0..63
  int lo = 0, hi = n;
  while (lo < hi) {
    int mid = (lo + hi) >> 1;
    if (batch[mid] < g) lo = mid + 1; else hi = mid;
  }
  gstart[g] = lo;
  if (g == 63) gstart[64] = n;
}

// 16 blocks per graph; float4 lanes; one atomicAdd per channel per block.
__global__ __launch_bounds__(256) void pool_sum_kernel(const float* __restrict__ Hf,
                                                       const int* __restrict__ gstart,
                                                       float* __restrict__ pool) {
  __shared__ float red[8 * 128];
  int g = blockIdx.x >> 4;
  int slice = blockIdx.x & 15;
  int t = threadIdx.x;
  int grp = t >> 5;        // 0..7: node stripe
  int cq = t & 31;         // channel quad
  int s = gstart[g], e = gstart[g + 1];
  int cnt = e - s;
  int per = (cnt + 15) >> 4;
  int ss = s + slice * per;
  int ee = ss + per; if (ee > e) ee = e;

  float4 acc = make_float4(0.f, 0.f, 0.f, 0.f);
  const float4* H4 = (const float4*)Hf;
  for (int nd = ss + grp; nd < ee; nd += 8) {
    float4 v = H4[(size_t)nd * 32 + cq];
    acc.x += v.x; acc.y += v.y; acc.z += v.z; acc.w += v.w;
  }
  *(float4*)&red[grp * 128 + cq * 4] = acc;
  __syncthreads();
  if (t < 128) {
    float tot = 0.f;
#pragma unroll
    for (int g8 = 0; g8 < 8; ++g8) tot += red[g8 * 128 + t];
    if (tot != 0.f) atomicAdd(&pool[g * 128 + t], tot);
  }
}

__global__ __launch_bounds__(128) void fc_kernel(const float* __restrict__ pool,
                                                 const int* __restrict__ gstart,
                                                 const float* __restrict__ fcW,
                                                 const float* __restrict__ fcb,
                                                 float* __restrict__ out) {
  __shared__ float p[128];
  int g = blockIdx.x;
  int t = threadIdx.x;
  int cnt = gstart[g + 1] - gstart[g];
  float inv = 1.0f / (float)((cnt > 0) ? cnt : 1);
  p[t] = pool[g * 128 + t] * inv;
  __syncthreads();
  if (t < 10) {
    float s = fcb[t];
    for (int c = 0; c < 128; ++c) s += p[c] * fcW[c * 10 + t];
    out[g * 10 + t] = s;
  }
}

// ---------------------------------------------------------------------------

extern "C" void kernel_launch(void* const* d_in, const int* in_sizes, int n_in,
                              void* d_out, int out_size, void* d_ws, size_t ws_size,
                              hipStream_t stream) {
  const float* x   = (const float*)d_in[0];
  const int* eidx  = (const int*)d_in[1];
  const int* batch = (const int*)d_in[2];
  const float* Wk1 = (const float*)d_in[3];  const float* bk1 = (const float*)d_in[4];
  const float* Wq1 = (const float*)d_in[5];  const float* bq1 = (const float*)d_in[6];
  const float* Wv1 = (const float*)d_in[7];  const float* bv1 = (const float*)d_in[8];
  const float* Ws1 = (const float*)d_in[9];  const float* bs1 = (const float*)d_in[10];
  const float* b1  = (const float*)d_in[11];
  const float* Wk2 = (const float*)d_in[12]; const float* bk2 = (const float*)d_in[13];
  const float* Wq2 = (const float*)d_in[14]; const float* bq2 = (const float*)d_in[15];
  const float* Wv2 = (const float*)d_in[16]; const float* bv2 = (const float*)d_in[17];
  const float* Ws2 = (const float*)d_in[18]; const float* bs2 = (const float*)d_in[19];
  const float* b2  = (const float*)d_in[20];
  const float* fcW = (const float*)d_in[21]; const float* fcb = (const float*)d_in[22];
  float* out = (float*)d_out;

  const int N = in_sizes[0] / 128;   // 50000
  const int E = in_sizes[1] / 2;     // 800000
  const int* src = eidx;
  const int* dst = eidx + E;

  // ---- workspace carve ----
  char* w = (char*)d_ws;
  size_t off = 0;
  auto carve = [&](size_t bytes) -> void* {
    void* p = w + off;
    off += (bytes + 255) & ~size_t(255);
    return p;
  };
  const size_t featB16 = (size_t)N * 128 * 2;
  const size_t featB32 = (size_t)N * 128 * 4;
  unsigned short* Xb = (unsigned short*)carve(featB16);
  unsigned short* Kb = (unsigned short*)carve(featB16);
  unsigned short* Qb = (unsigned short*)carve(featB16);
  unsigned short* Vb = (unsigned short*)carve(featB16);
  unsigned short* Hb = (unsigned short*)carve(featB16);
  float* S  = (float*)carve(featB32);
  float* Hf = (float*)carve(featB32);
  unsigned short* WT = (unsigned short*)carve(2 * 4 * 128 * 128 * 2);
  float* bcat = (float*)carve(1024 * 4);
  int* cnt      = (int*)carve((size_t)N * 4);
  int* row_ptr  = (int*)carve((size_t)(N + 1) * 4);
  int* cursor   = (int*)carve((size_t)N * 4);
  int* tmp_excl = (int*)carve((size_t)N * 4);
  int* bsum     = (int*)carve(256 * 4);
  int* boff     = (int*)carve(256 * 4);
  int* es       = (int*)carve((size_t)E * 4);
  int* gstart   = (int*)carve(65 * 4);
  float* pool   = (float*)carve(64 * 128 * 4);
  (void)ws_size; (void)n_in; (void)out_size;

  hipMemsetAsync(cnt, 0, (size_t)N * 4, stream);
  hipMemsetAsync(pool, 0, 64 * 128 * 4, stream);

  // ---- prep: CSR + dtype packing ----
  int nb512 = (N + 511) / 512;
  hist_kernel<<<(E + 255) / 256, 256, 0, stream>>>(dst, cnt, E);
  scan1_kernel<<<nb512, 256, 0, stream>>>(cnt, tmp_excl, bsum, N);
  scan2_kernel<<<1, 128, 0, stream>>>(bsum, boff, nb512);
  finalize_rp_kernel<<<(N + 255) / 256, 256, 0, stream>>>(tmp_excl, boff, row_ptr, cursor, N, E);
  scatter_kernel<<<(E + 255) / 256, 256, 0, stream>>>(src, dst, cursor, es, E);

  convert_kernel<<<(N * 32 + 255) / 256, 256, 0, stream>>>(x, Xb, N * 32);
  prepack_w_kernel<<<512, 256, 0, stream>>>(Wk1, Wq1, Wv1, Ws1, Wk2, Wq2, Wv2, Ws2, WT);
  prepack_b_kernel<<<4, 256, 0, stream>>>(bk1, bq1, bv1, bs1, b1,
                                          bk2, bq2, bv2, bs2, b2, bcat);

  dim3 ggrid((N + 127) / 128, 4);

  // ---- layer 1 ----
  gemm_mfma_kernel<<<ggrid, 256, 0, stream>>>(Xb, WT, bcat, Kb, Qb, Vb, S, N);
  edge_agg_kernel<<<(N + 3) / 4, 256, 0, stream>>>(Kb, Qb, Vb, S, row_ptr, es,
                                                   Hb, Hf, 0, N);

  // ---- layer 2 ----
  gemm_mfma_kernel<<<ggrid, 256, 0, stream>>>(Hb, WT + 65536, bcat + 512,
                                              Kb, Qb, Vb, S, N);
  edge_agg_kernel<<<(N + 3) / 4, 256, 0, stream>>>(Kb, Qb, Vb, S, row_ptr, es,
                                                   Hb, Hf, 1, N);

  // ---- pool + fc ----
  graph_bounds_kernel<<<1, 64, 0, stream>>>(batch, gstart, N);
  pool_sum_kernel<<<1024, 256, 0, stream>>>(Hf, gstart, pool);
  fc_kernel<<<64, 128, 0, stream>>>(pool, gstart, fcW, fcb, out);
}

// Round 5
// 427.586 us; speedup vs baseline: 2.7444x; 1.0095x over previous
//
#include <hip/hip_runtime.h>
#include <math.h>

// ---------------------------------------------------------------------------
// ResGatedGraphConv x2 + global_mean_pool + FC.
// R2: GEMMs via bf16 MFMA; K/Q/V bf16; S fp32.
// R3: pool 16 blocks/graph; edge_agg 4 edges/wave (ushort8 lanes).
// R4: rcp/exp2-based sigmoid (fp32 div was ~4x VALU cost), fused prep kernel,
//     gemm LDS union (aT/estage) for 4 blocks/CU, binary-search graph bounds.
// ---------------------------------------------------------------------------

typedef __attribute__((ext_vector_type(8))) short short8;
typedef __attribute__((ext_vector_type(4))) float floatx4;
typedef __attribute__((ext_vector_type(8))) float floatx8;
typedef __attribute__((ext_vector_type(8))) unsigned short ushort8v;

#define LOG2E 1.4426950408889634f

__device__ __forceinline__ unsigned short f2b(float f) {
  unsigned int u = __builtin_bit_cast(unsigned int, f);
  u += 0x7fff + ((u >> 16) & 1);   // RNE
  return (unsigned short)(u >> 16);
}
__device__ __forceinline__ float b2f(unsigned short u) {
  return __builtin_bit_cast(float, ((unsigned int)u) << 16);
}

// ---------------- CSR build ----------------

__global__ __launch_bounds__(256) void hist_kernel(const int* __restrict__ dst,
                                                   int* __restrict__ cnt, int E) {
  int e = blockIdx.x * 256 + threadIdx.x;
  if (e < E) atomicAdd(&cnt[dst[e]], 1);
}

__global__ __launch_bounds__(256) void scan1_kernel(const int* __restrict__ cnt,
                                                    int* __restrict__ tmp_excl,
                                                    int* __restrict__ bsum, int n) {
  __shared__ int s[256];
  int t = threadIdx.x;
  int base = blockIdx.x * 512;
  int i0 = base + 2 * t, i1 = i0 + 1;
  int a0 = (i0 < n) ? cnt[i0] : 0;
  int a1 = (i1 < n) ? cnt[i1] : 0;
  int sum = a0 + a1;
  s[t] = sum;
  __syncthreads();
  for (int off = 1; off < 256; off <<= 1) {
    int v = (t >= off) ? s[t - off] : 0;
    __syncthreads();
    s[t] += v;
    __syncthreads();
  }
  int excl = s[t] - sum;
  if (i0 < n) tmp_excl[i0] = excl;
  if (i1 < n) tmp_excl[i1] = excl + a0;
  if (t == 255) bsum[blockIdx.x] = s[255];
}

__global__ __launch_bounds__(128) void scan2_kernel(const int* __restrict__ bsum,
                                                    int* __restrict__ boff, int nb) {
  __shared__ int s[128];
  int t = threadIdx.x;
  int v = (t < nb) ? bsum[t] : 0;
  s[t] = v;
  __syncthreads();
  for (int off = 1; off < 128; off <<= 1) {
    int u = (t >= off) ? s[t - off] : 0;
    __syncthreads();
    s[t] += u;
    __syncthreads();
  }
  if (t < nb) boff[t] = s[t] - v;
}

__global__ __launch_bounds__(256) void finalize_rp_kernel(const int* __restrict__ tmp_excl,
                                                          const int* __restrict__ boff,
                                                          int* __restrict__ row_ptr,
                                                          int* __restrict__ cursor,
                                                          int n, int E) {
  int i = blockIdx.x * 256 + threadIdx.x;
  if (i < n) {
    int v = tmp_excl[i] + boff[i >> 9];
    row_ptr[i] = v;
    cursor[i] = v;
  }
  if (i == 0) row_ptr[n] = E;
}

__global__ __launch_bounds__(256) void scatter_kernel(const int* __restrict__ src,
                                                      const int* __restrict__ dst,
                                                      int* __restrict__ cursor,
                                                      int* __restrict__ es, int E) {
  int e = blockIdx.x * 256 + threadIdx.x;
  if (e < E) {
    int i = dst[e];
    int p = atomicAdd(&cursor[i], 1);
    es[p] = src[e];
  }
}

// ---------------- fused prep: x->bf16 | pack W bf16 [n][k] | pack biases ----

__global__ __launch_bounds__(256) void prep_kernel(
    const float* __restrict__ X, unsigned short* __restrict__ Xb, int total4,
    const float* __restrict__ Wk1, const float* __restrict__ Wq1,
    const float* __restrict__ Wv1, const float* __restrict__ Ws1,
    const float* __restrict__ Wk2, const float* __restrict__ Wq2,
    const float* __restrict__ Wv2, const float* __restrict__ Ws2,
    unsigned short* __restrict__ WT,
    const float* __restrict__ bk1, const float* __restrict__ bq1,
    const float* __restrict__ bv1, const float* __restrict__ bs1,
    const float* __restrict__ b1,
    const float* __restrict__ bk2, const float* __restrict__ bq2,
    const float* __restrict__ bv2, const float* __restrict__ bs2,
    const float* __restrict__ b2,
    float* __restrict__ bcat, int nconvb) {
  int b = blockIdx.x;
  if (b < nconvb) {
    int i = b * 256 + threadIdx.x;
    if (i < total4) {
      float4 v = ((const float4*)X)[i];
      ushort4 o;
      o.x = f2b(v.x); o.y = f2b(v.y); o.z = f2b(v.z); o.w = f2b(v.w);
      ((ushort4*)Xb)[i] = o;
    }
    return;
  }
  b -= nconvb;
  if (b < 512) {
    int idx = b * 256 + threadIdx.x;   // 0 .. 131071
    int layer = idx >> 16;
    int rem = idx & 0xFFFF;
    int mat = rem >> 14;
    int nk = rem & 0x3FFF;
    int nn = nk >> 7, kk = nk & 127;
    int sel = layer * 4 + mat;
    const float* W = (sel == 0) ? Wk1 : (sel == 1) ? Wq1 : (sel == 2) ? Wv1 :
                     (sel == 3) ? Ws1 : (sel == 4) ? Wk2 : (sel == 5) ? Wq2 :
                     (sel == 6) ? Wv2 : Ws2;
    WT[idx] = f2b(W[kk * 128 + nn]);
    return;
  }
  b -= 512;
  {
    int idx = b * 256 + threadIdx.x;   // 0 .. 1023
    if (idx >= 1024) return;
    int layer = idx >> 9;
    int rem = idx & 511;
    int mat = rem >> 7, c = rem & 127;
    int sel = layer * 4 + mat;
    const float* bb = (sel == 0) ? bk1 : (sel == 1) ? bq1 : (sel == 2) ? bv1 :
                      (sel == 3) ? bs1 : (sel == 4) ? bk2 : (sel == 5) ? bq2 :
                      (sel == 6) ? bv2 : bs2;
    float v = bb[c];
    if (mat == 3) v += (layer == 0) ? b1[c] : b2[c];
    bcat[idx] = v;
  }
}

// ---------------- MFMA GEMM: [n x 128] bf16 @ WT[mat] -> K/Q/V (bf16), S (f32)

__global__ __launch_bounds__(256) void gemm_mfma_kernel(
    const unsigned short* __restrict__ Xb,   // [n][128] bf16
    const unsigned short* __restrict__ WT,   // [4][128 n][128 k] bf16
    const float* __restrict__ bcat,          // [4][128]
    unsigned short* __restrict__ Kb, unsigned short* __restrict__ Qb,
    unsigned short* __restrict__ Vb, float* __restrict__ S, int n) {
  __shared__ unsigned short aT[128 * 136];   // 34 KB; aliased by epilogue stage

  int t = threadIdx.x;
  int row0 = blockIdx.x * 128;
  int m = blockIdx.y;

#pragma unroll
  for (int i = 0; i < 8; ++i) {
    int c = i * 256 + t;          // 16B chunk id, 0..2047
    int r = c >> 4, col16 = c & 15;
    int4 v = make_int4(0, 0, 0, 0);
    if (row0 + r < n) v = *(const int4*)&Xb[(size_t)(row0 + r) * 128 + col16 * 8];
    *(int4*)&aT[r * 136 + col16 * 8] = v;
  }
  __syncthreads();

  int lane = t & 63, wid = t >> 6;
  int wy = wid >> 1, wx = wid & 1;
  int l15 = lane & 15, lq = lane >> 4;

  const unsigned short* WTm = WT + (size_t)m * 16384;

  floatx4 acc[4][4];
#pragma unroll
  for (int mf = 0; mf < 4; ++mf)
#pragma unroll
    for (int nf = 0; nf < 4; ++nf) acc[mf][nf] = (floatx4)(0.0f);

#pragma unroll
  for (int ks = 0; ks < 4; ++ks) {
    int kof = ks * 32 + lq * 8;
    short8 a[4], b[4];
#pragma unroll
    for (int mf = 0; mf < 4; ++mf)
      a[mf] = *(const short8*)&aT[(wy * 64 + mf * 16 + l15) * 136 + kof];
#pragma unroll
    for (int nf = 0; nf < 4; ++nf)
      b[nf] = *(const short8*)&WTm[(size_t)(wx * 64 + nf * 16 + l15) * 128 + kof];
#pragma unroll
    for (int mf = 0; mf < 4; ++mf)
#pragma unroll
      for (int nf = 0; nf < 4; ++nf)
        acc[mf][nf] = __builtin_amdgcn_mfma_f32_16x16x32_bf16(a[mf], b[nf], acc[mf][nf], 0, 0, 0);
  }

  // all aT reads done chip-wide before aliasing it as the epilogue stage
  __syncthreads();
  float* estage = (float*)aT + (size_t)wid * 1088;   // 16*68 floats per wave

  const float* bias = bcat + m * 128;
  int r4 = lane >> 2, cq4 = lane & 3;
  int col = wx * 64 + cq4 * 16;
  float4 bv[4];
#pragma unroll
  for (int j = 0; j < 4; ++j) bv[j] = *(const float4*)&bias[col + j * 4];

  unsigned short* Ob = (m == 0) ? Kb : (m == 1) ? Qb : Vb;

#pragma unroll
  for (int mf = 0; mf < 4; ++mf) {
#pragma unroll
    for (int nf = 0; nf < 4; ++nf)
#pragma unroll
      for (int i = 0; i < 4; ++i)
        estage[(lq * 4 + i) * 68 + nf * 16 + l15] = acc[mf][nf][i];
    // per-wave region, wave-lockstep: no barrier needed
    int grow = row0 + wy * 64 + mf * 16 + r4;
    if (grow < n) {
      float4 p[4];
#pragma unroll
      for (int j = 0; j < 4; ++j) {
        float4 e = *(const float4*)&estage[r4 * 68 + cq4 * 16 + j * 4];
        p[j].x = e.x + bv[j].x; p[j].y = e.y + bv[j].y;
        p[j].z = e.z + bv[j].z; p[j].w = e.w + bv[j].w;
      }
      if (m < 3) {
        ushort8v o0, o1;
        o0[0] = f2b(p[0].x); o0[1] = f2b(p[0].y); o0[2] = f2b(p[0].z); o0[3] = f2b(p[0].w);
        o0[4] = f2b(p[1].x); o0[5] = f2b(p[1].y); o0[6] = f2b(p[1].z); o0[7] = f2b(p[1].w);
        o1[0] = f2b(p[2].x); o1[1] = f2b(p[2].y); o1[2] = f2b(p[2].z); o1[3] = f2b(p[2].w);
        o1[4] = f2b(p[3].x); o1[5] = f2b(p[3].y); o1[6] = f2b(p[3].z); o1[7] = f2b(p[3].w);
        *(ushort8v*)&Ob[(size_t)grow * 128 + col] = o0;
        *(ushort8v*)&Ob[(size_t)grow * 128 + col + 8] = o1;
      } else {
#pragma unroll
        for (int j = 0; j < 4; ++j)
          *(float4*)&S[(size_t)grow * 128 + col + j * 4] = p[j];
      }
    }
  }
}

// ---------------- edge aggregation + residual + relu ----------------
// h[i] = relu( S[i] + sum_j sigmoid(K[i]+Q[j]) * V[j] )
// One node per wave; 4 edge slots (16 lanes x ushort8 = 256B row each).
// sigmoid via native v_exp_f32 (2^x) + v_rcp_f32: fp32 div is ~4x slower.

__global__ __launch_bounds__(256) void edge_agg_kernel(
    const unsigned short* __restrict__ Kb, const unsigned short* __restrict__ Qb,
    const unsigned short* __restrict__ Vb, const float* __restrict__ S,
    const int* __restrict__ row_ptr, const int* __restrict__ es,
    unsigned short* __restrict__ Hb, float* __restrict__ Hf, int mode, int n) {
  int wid = threadIdx.x >> 6;
  int lane = threadIdx.x & 63;
  int node = blockIdx.x * 4 + wid;
  if (node >= n) return;
  int grp = lane >> 4;     // edge slot 0..3
  int l16 = lane & 15;     // channels l16*8 .. l16*8+7

  ushort8v kr = *(const ushort8v*)&Kb[(size_t)node * 128 + l16 * 8];
  float kcn[8];
#pragma unroll
  for (int i = 0; i < 8; ++i) kcn[i] = b2f(kr[i]) * (-LOG2E);

  floatx8 acc = (floatx8)(0.0f);

  int e0 = row_ptr[node], e1 = row_ptr[node + 1];
  int e = e0 + grp;
  int j = (e < e1) ? es[e] : -1;
  while (j >= 0) {
    int en = e + 4;
    int jn = (en < e1) ? es[en] : -1;
    ushort8v q8 = *(const ushort8v*)&Qb[(size_t)j * 128 + l16 * 8];
    ushort8v v8 = *(const ushort8v*)&Vb[(size_t)j * 128 + l16 * 8];
#pragma unroll
    for (int i = 0; i < 8; ++i) {
      float q = b2f(q8[i]);
      float v = b2f(v8[i]);
      float ex = __builtin_amdgcn_exp2f(fmaf(q, -LOG2E, kcn[i]));
      acc[i] = fmaf(v, __builtin_amdgcn_rcpf(1.0f + ex), acc[i]);
    }
    e = en; j = jn;
  }

  // combine 4 edge slots
#pragma unroll
  for (int i = 0; i < 8; ++i) {
    acc[i] += __shfl_xor(acc[i], 16);
    acc[i] += __shfl_xor(acc[i], 32);
  }

  if (grp == 0) {
    float4 s0 = *(const float4*)&S[(size_t)node * 128 + l16 * 8];
    float4 s1 = *(const float4*)&S[(size_t)node * 128 + l16 * 8 + 4];
    float r[8];
    r[0] = fmaxf(acc[0] + s0.x, 0.f); r[1] = fmaxf(acc[1] + s0.y, 0.f);
    r[2] = fmaxf(acc[2] + s0.z, 0.f); r[3] = fmaxf(acc[3] + s0.w, 0.f);
    r[4] = fmaxf(acc[4] + s1.x, 0.f); r[5] = fmaxf(acc[5] + s1.y, 0.f);
    r[6] = fmaxf(acc[6] + s1.z, 0.f); r[7] = fmaxf(acc[7] + s1.w, 0.f);
    if (mode == 0) {
      ushort8v o;
#pragma unroll
      for (int i = 0; i < 8; ++i) o[i] = f2b(r[i]);
      *(ushort8v*)&Hb[(size_t)node * 128 + l16 * 8] = o;
    } else {
      float4 h0 = make_float4(r[0], r[1], r[2], r[3]);
      float4 h1 = make_float4(r[4], r[5], r[6], r[7]);
      *(float4*)&Hf[(size_t)node * 128 + l16 * 8] = h0;
      *(float4*)&Hf[(size_t)node * 128 + l16 * 8 + 4] = h1;
    }
  }
}

// ---------------- mean pool + FC (graph bounds via binary search) ----------

__device__ __forceinline__ int lb_batch(const int* __restrict__ batch, int n, int key) {
  int lo = 0, hi = n;
  while (lo < hi) {
    int mid = (lo + hi) >> 1;
    if (batch[mid] < key) lo = mid + 1; else hi = mid;
  }
  return lo;
}

// 16 blocks per graph; float4 lanes; one atomicAdd per channel per block.
__global__ __launch_bounds__(256) void pool_sum_kernel(const float* __restrict__ Hf,
                                                       const int* __restrict__ batch,
                                                       float* __restrict__ pool, int n) {
  __shared__ float red[8 * 128];
  int g = blockIdx.x >> 4;
  int slice = blockIdx.x & 15;
  int t = threadIdx.x;
  int grp = t >> 5;        // 0..7: node stripe
  int cq = t & 31;         // channel quad
  int s = lb_batch(batch, n, g), e = lb_batch(batch, n, g + 1);
  int cnt = e - s;
  int per = (cnt + 15) >> 4;
  int ss = s + slice * per;
  int ee = ss + per; if (ee > e) ee = e;

  float4 acc = make_float4(0.f, 0.f, 0.f, 0.f);
  const float4* H4 = (const float4*)Hf;
  for (int nd = ss + grp; nd < ee; nd += 8) {
    float4 v = H4[(size_t)nd * 32 + cq];
    acc.x += v.x; acc.y += v.y; acc.z += v.z; acc.w += v.w;
  }
  *(float4*)&red[grp * 128 + cq * 4] = acc;
  __syncthreads();
  if (t < 128) {
    float tot = 0.f;
#pragma unroll
    for (int g8 = 0; g8 < 8; ++g8) tot += red[g8 * 128 + t];
    if (tot != 0.f) atomicAdd(&pool[g * 128 + t], tot);
  }
}

__global__ __launch_bounds__(128) void fc_kernel(const float* __restrict__ pool,
                                                 const int* __restrict__ batch,
                                                 const float* __restrict__ fcW,
                                                 const float* __restrict__ fcb,
                                                 float* __restrict__ out, int n) {
  __shared__ float p[128];
  int g = blockIdx.x;
  int t = threadIdx.x;
  int cnt = lb_batch(batch, n, g + 1) - lb_batch(batch, n, g);
  float inv = 1.0f / (float)((cnt > 0) ? cnt : 1);
  p[t] = pool[g * 128 + t] * inv;
  __syncthreads();
  if (t < 10) {
    float s = fcb[t];
    for (int c = 0; c < 128; ++c) s += p[c] * fcW[c * 10 + t];
    out[g * 10 + t] = s;
  }
}

// ---------------------------------------------------------------------------

extern "C" void kernel_launch(void* const* d_in, const int* in_sizes, int n_in,
                              void* d_out, int out_size, void* d_ws, size_t ws_size,
                              hipStream_t stream) {
  const float* x   = (const float*)d_in[0];
  const int* eidx  = (const int*)d_in[1];
  const int* batch = (const int*)d_in[2];
  const float* Wk1 = (const float*)d_in[3];  const float* bk1 = (const float*)d_in[4];
  const float* Wq1 = (const float*)d_in[5];  const float* bq1 = (const float*)d_in[6];
  const float* Wv1 = (const float*)d_in[7];  const float* bv1 = (const float*)d_in[8];
  const float* Ws1 = (const float*)d_in[9];  const float* bs1 = (const float*)d_in[10];
  const float* b1  = (const float*)d_in[11];
  const float* Wk2 = (const float*)d_in[12]; const float* bk2 = (const float*)d_in[13];
  const float* Wq2 = (const float*)d_in[14]; const float* bq2 = (const float*)d_in[15];
  const float* Wv2 = (const float*)d_in[16]; const float* bv2 = (const float*)d_in[17];
  const float* Ws2 = (const float*)d_in[18]; const float* bs2 = (const float*)d_in[19];
  const float* b2  = (const float*)d_in[20];
  const float* fcW = (const float*)d_in[21]; const float* fcb = (const float*)d_in[22];
  float* out = (float*)d_out;

  const int N = in_sizes[0] / 128;   // 50000
  const int E = in_sizes[1] / 2;     // 800000
  const int* src = eidx;
  const int* dst = eidx + E;

  // ---- workspace carve ----
  char* w = (char*)d_ws;
  size_t off = 0;
  auto carve = [&](size_t bytes) -> void* {
    void* p = w + off;
    off += (bytes + 255) & ~size_t(255);
    return p;
  };
  const size_t featB16 = (size_t)N * 128 * 2;
  const size_t featB32 = (size_t)N * 128 * 4;
  unsigned short* Xb = (unsigned short*)carve(featB16);
  unsigned short* Kb = (unsigned short*)carve(featB16);
  unsigned short* Qb = (unsigned short*)carve(featB16);
  unsigned short* Vb = (unsigned short*)carve(featB16);
  unsigned short* Hb = (unsigned short*)carve(featB16);
  float* S  = (float*)carve(featB32);
  float* Hf = (float*)carve(featB32);
  unsigned short* WT = (unsigned short*)carve(2 * 4 * 128 * 128 * 2);
  float* bcat = (float*)carve(1024 * 4);
  int* cnt      = (int*)carve((size_t)N * 4);
  int* row_ptr  = (int*)carve((size_t)(N + 1) * 4);
  int* cursor   = (int*)carve((size_t)N * 4);
  int* tmp_excl = (int*)carve((size_t)N * 4);
  int* bsum     = (int*)carve(256 * 4);
  int* boff     = (int*)carve(256 * 4);
  int* es       = (int*)carve((size_t)E * 4);
  float* pool   = (float*)carve(64 * 128 * 4);
  (void)ws_size; (void)n_in; (void)out_size;

  hipMemsetAsync(cnt, 0, (size_t)N * 4, stream);
  hipMemsetAsync(pool, 0, 64 * 128 * 4, stream);

  // ---- prep: CSR + dtype packing ----
  int nb512 = (N + 511) / 512;
  hist_kernel<<<(E + 255) / 256, 256, 0, stream>>>(dst, cnt, E);
  scan1_kernel<<<nb512, 256, 0, stream>>>(cnt, tmp_excl, bsum, N);
  scan2_kernel<<<1, 128, 0, stream>>>(bsum, boff, nb512);
  finalize_rp_kernel<<<(N + 255) / 256, 256, 0, stream>>>(tmp_excl, boff, row_ptr, cursor, N, E);
  scatter_kernel<<<(E + 255) / 256, 256, 0, stream>>>(src, dst, cursor, es, E);

  int nconvb = (N * 32 + 255) / 256;
  prep_kernel<<<nconvb + 512 + 4, 256, 0, stream>>>(
      x, Xb, N * 32,
      Wk1, Wq1, Wv1, Ws1, Wk2, Wq2, Wv2, Ws2, WT,
      bk1, bq1, bv1, bs1, b1, bk2, bq2, bv2, bs2, b2, bcat, nconvb);

  dim3 ggrid((N + 127) / 128, 4);

  // ---- layer 1 ----
  gemm_mfma_kernel<<<ggrid, 256, 0, stream>>>(Xb, WT, bcat, Kb, Qb, Vb, S, N);
  edge_agg_kernel<<<(N + 3) / 4, 256, 0, stream>>>(Kb, Qb, Vb, S, row_ptr, es,
                                                   Hb, Hf, 0, N);

  // ---- layer 2 ----
  gemm_mfma_kernel<<<ggrid, 256, 0, stream>>>(Hb, WT + 65536, bcat + 512,
                                              Kb, Qb, Vb, S, N);
  edge_agg_kernel<<<(N + 3) / 4, 256, 0, stream>>>(Kb, Qb, Vb, S, row_ptr, es,
                                                   Hb, Hf, 1, N);

  // ---- pool + fc ----
  pool_sum_kernel<<<1024, 256, 0, stream>>>(Hf, batch, pool, N);
  fc_kernel<<<64, 128, 0, stream>>>(pool, batch, fcW, fcb, out, N);
}

// Round 6
// 423.816 us; speedup vs baseline: 2.7689x; 1.0089x over previous
//
#include <hip/hip_runtime.h>
#include <math.h>

// ---------------------------------------------------------------------------
// ResGatedGraphConv x2 + global_mean_pool + FC.
// R2: GEMMs via bf16 MFMA; K/Q/V bf16; S fp32 residual.
// R4: rcp/exp2 sigmoid; fused prep.
// R5: edge_agg 8 slots x 8 lanes (2x gather MLP) + packed bf16 unpack;
//     H bf16-only (no Hf); pool via per-slice partials (no atomics/memset);
//     scan2 merged into finalize; cnt zeroing folded into prep. 11 dispatches.
// ---------------------------------------------------------------------------

typedef __attribute__((ext_vector_type(8))) short short8;
typedef __attribute__((ext_vector_type(4))) float floatx4;
typedef __attribute__((ext_vector_type(8))) unsigned short ushort8v;

#define LOG2E 1.4426950408889634f

__device__ __forceinline__ unsigned short f2b(float f) {
  unsigned int u = __builtin_bit_cast(unsigned int, f);
  u += 0x7fff + ((u >> 16) & 1);   // RNE
  return (unsigned short)(u >> 16);
}
__device__ __forceinline__ float b2f(unsigned short u) {
  return __builtin_bit_cast(float, ((unsigned int)u) << 16);
}
// packed bf16 pair unpack: element 0 = low 16 bits
__device__ __forceinline__ float blo(unsigned int u) {
  return __builtin_bit_cast(float, u << 16);
}
__device__ __forceinline__ float bhi(unsigned int u) {
  return __builtin_bit_cast(float, u & 0xffff0000u);
}

// ---------------- CSR build ----------------

__global__ __launch_bounds__(256) void hist_kernel(const int* __restrict__ dst,
                                                   int* __restrict__ cnt, int E) {
  int e = blockIdx.x * 256 + threadIdx.x;
  if (e < E) atomicAdd(&cnt[dst[e]], 1);
}

// per-512-chunk exclusive scan + chunk totals
__global__ __launch_bounds__(256) void scan1_kernel(const int* __restrict__ cnt,
                                                    int* __restrict__ tmp_excl,
                                                    int* __restrict__ bsum, int n) {
  __shared__ int s[256];
  int t = threadIdx.x;
  int base = blockIdx.x * 512;
  int i0 = base + 2 * t, i1 = i0 + 1;
  int a0 = (i0 < n) ? cnt[i0] : 0;
  int a1 = (i1 < n) ? cnt[i1] : 0;
  int sum = a0 + a1;
  s[t] = sum;
  __syncthreads();
  for (int off = 1; off < 256; off <<= 1) {
    int v = (t >= off) ? s[t - off] : 0;
    __syncthreads();
    s[t] += v;
    __syncthreads();
  }
  int excl = s[t] - sum;
  if (i0 < n) tmp_excl[i0] = excl;
  if (i1 < n) tmp_excl[i1] = excl + a0;
  if (t == 255) bsum[blockIdx.x] = s[255];
}

// finalize + inline scan of bsum (each block redundantly scans <=128 chunks;
// a block's 256 elements live inside ONE 512-chunk, so one prefix per block)
__global__ __launch_bounds__(256) void finalize_rp_kernel(const int* __restrict__ tmp_excl,
                                                          const int* __restrict__ bsum,
                                                          int* __restrict__ row_ptr,
                                                          int* __restrict__ cursor,
                                                          int n, int E, int nb) {
  __shared__ int s[128];
  int t = threadIdx.x;
  if (t < 128) s[t] = (t < nb) ? bsum[t] : 0;
  __syncthreads();
  for (int off = 1; off < 128; off <<= 1) {
    int v = (t < 128 && t >= off) ? s[t - off] : 0;
    __syncthreads();
    if (t < 128) s[t] += v;
    __syncthreads();
  }
  int chunk = blockIdx.x >> 1;
  int boff = (chunk == 0) ? 0 : s[chunk - 1];
  int i = blockIdx.x * 256 + t;
  if (i < n) {
    int v = tmp_excl[i] + boff;
    row_ptr[i] = v;
    cursor[i] = v;
  }
  if (i == 0) row_ptr[n] = E;
}

__global__ __launch_bounds__(256) void scatter_kernel(const int* __restrict__ src,
                                                      const int* __restrict__ dst,
                                                      int* __restrict__ cursor,
                                                      int* __restrict__ es, int E) {
  int e = blockIdx.x * 256 + threadIdx.x;
  if (e < E) {
    int i = dst[e];
    int p = atomicAdd(&cursor[i], 1);
    es[p] = src[e];
  }
}

// ---------------- fused prep: x->bf16 | pack W | pack biases | zero cnt ----

__global__ __launch_bounds__(256) void prep_kernel(
    const float* __restrict__ X, unsigned short* __restrict__ Xb, int total4,
    const float* __restrict__ Wk1, const float* __restrict__ Wq1,
    const float* __restrict__ Wv1, const float* __restrict__ Ws1,
    const float* __restrict__ Wk2, const float* __restrict__ Wq2,
    const float* __restrict__ Wv2, const float* __restrict__ Ws2,
    unsigned short* __restrict__ WT,
    const float* __restrict__ bk1, const float* __restrict__ bq1,
    const float* __restrict__ bv1, const float* __restrict__ bs1,
    const float* __restrict__ b1,
    const float* __restrict__ bk2, const float* __restrict__ bq2,
    const float* __restrict__ bv2, const float* __restrict__ bs2,
    const float* __restrict__ b2,
    float* __restrict__ bcat,
    int* __restrict__ cnt, int ncnt4, int nconvb, int nzerob) {
  int b = blockIdx.x;
  if (b < nconvb) {
    int i = b * 256 + threadIdx.x;
    if (i < total4) {
      float4 v = ((const float4*)X)[i];
      ushort4 o;
      o.x = f2b(v.x); o.y = f2b(v.y); o.z = f2b(v.z); o.w = f2b(v.w);
      ((ushort4*)Xb)[i] = o;
    }
    return;
  }
  b -= nconvb;
  if (b < nzerob) {
    int i = b * 256 + threadIdx.x;
    if (i < ncnt4) ((int4*)cnt)[i] = make_int4(0, 0, 0, 0);
    return;
  }
  b -= nzerob;
  if (b < 512) {
    int idx = b * 256 + threadIdx.x;   // 0 .. 131071
    int layer = idx >> 16;
    int rem = idx & 0xFFFF;
    int mat = rem >> 14;
    int nk = rem & 0x3FFF;
    int nn = nk >> 7, kk = nk & 127;
    int sel = layer * 4 + mat;
    const float* W = (sel == 0) ? Wk1 : (sel == 1) ? Wq1 : (sel == 2) ? Wv1 :
                     (sel == 3) ? Ws1 : (sel == 4) ? Wk2 : (sel == 5) ? Wq2 :
                     (sel == 6) ? Wv2 : Ws2;
    WT[idx] = f2b(W[kk * 128 + nn]);
    return;
  }
  b -= 512;
  {
    int idx = b * 256 + threadIdx.x;   // 0 .. 1023
    if (idx >= 1024) return;
    int layer = idx >> 9;
    int rem = idx & 511;
    int mat = rem >> 7, c = rem & 127;
    int sel = layer * 4 + mat;
    const float* bb = (sel == 0) ? bk1 : (sel == 1) ? bq1 : (sel == 2) ? bv1 :
                      (sel == 3) ? bs1 : (sel == 4) ? bk2 : (sel == 5) ? bq2 :
                      (sel == 6) ? bv2 : bs2;
    float v = bb[c];
    if (mat == 3) v += (layer == 0) ? b1[c] : b2[c];
    bcat[idx] = v;
  }
}

// ---------------- MFMA GEMM: [n x 128] bf16 @ WT[mat] -> K/Q/V (bf16), S (f32)

__global__ __launch_bounds__(256) void gemm_mfma_kernel(
    const unsigned short* __restrict__ Xb,   // [n][128] bf16
    const unsigned short* __restrict__ WT,   // [4][128 n][128 k] bf16
    const float* __restrict__ bcat,          // [4][128]
    unsigned short* __restrict__ Kb, unsigned short* __restrict__ Qb,
    unsigned short* __restrict__ Vb, float* __restrict__ S, int n) {
  __shared__ unsigned short aT[128 * 136];   // 34 KB; aliased by epilogue stage

  int t = threadIdx.x;
  int row0 = blockIdx.x * 128;
  int m = blockIdx.y;

#pragma unroll
  for (int i = 0; i < 8; ++i) {
    int c = i * 256 + t;          // 16B chunk id, 0..2047
    int r = c >> 4, col16 = c & 15;
    int4 v = make_int4(0, 0, 0, 0);
    if (row0 + r < n) v = *(const int4*)&Xb[(size_t)(row0 + r) * 128 + col16 * 8];
    *(int4*)&aT[r * 136 + col16 * 8] = v;
  }
  __syncthreads();

  int lane = t & 63, wid = t >> 6;
  int wy = wid >> 1, wx = wid & 1;
  int l15 = lane & 15, lq = lane >> 4;

  const unsigned short* WTm = WT + (size_t)m * 16384;

  floatx4 acc[4][4];
#pragma unroll
  for (int mf = 0; mf < 4; ++mf)
#pragma unroll
    for (int nf = 0; nf < 4; ++nf) acc[mf][nf] = (floatx4)(0.0f);

#pragma unroll
  for (int ks = 0; ks < 4; ++ks) {
    int kof = ks * 32 + lq * 8;
    short8 a[4], b[4];
#pragma unroll
    for (int mf = 0; mf < 4; ++mf)
      a[mf] = *(const short8*)&aT[(wy * 64 + mf * 16 + l15) * 136 + kof];
#pragma unroll
    for (int nf = 0; nf < 4; ++nf)
      b[nf] = *(const short8*)&WTm[(size_t)(wx * 64 + nf * 16 + l15) * 128 + kof];
#pragma unroll
    for (int mf = 0; mf < 4; ++mf)
#pragma unroll
      for (int nf = 0; nf < 4; ++nf)
        acc[mf][nf] = __builtin_amdgcn_mfma_f32_16x16x32_bf16(a[mf], b[nf], acc[mf][nf], 0, 0, 0);
  }

  // all aT reads done before aliasing it as the epilogue stage
  __syncthreads();
  float* estage = (float*)aT + (size_t)wid * 1088;   // 16*68 floats per wave

  const float* bias = bcat + m * 128;
  int r4 = lane >> 2, cq4 = lane & 3;
  int col = wx * 64 + cq4 * 16;
  float4 bv[4];
#pragma unroll
  for (int j = 0; j < 4; ++j) bv[j] = *(const float4*)&bias[col + j * 4];

  unsigned short* Ob = (m == 0) ? Kb : (m == 1) ? Qb : Vb;

#pragma unroll
  for (int mf = 0; mf < 4; ++mf) {
#pragma unroll
    for (int nf = 0; nf < 4; ++nf)
#pragma unroll
      for (int i = 0; i < 4; ++i)
        estage[(lq * 4 + i) * 68 + nf * 16 + l15] = acc[mf][nf][i];
    // per-wave region, wave-lockstep: no barrier needed
    int grow = row0 + wy * 64 + mf * 16 + r4;
    if (grow < n) {
      float4 p[4];
#pragma unroll
      for (int j = 0; j < 4; ++j) {
        float4 e = *(const float4*)&estage[r4 * 68 + cq4 * 16 + j * 4];
        p[j].x = e.x + bv[j].x; p[j].y = e.y + bv[j].y;
        p[j].z = e.z + bv[j].z; p[j].w = e.w + bv[j].w;
      }
      if (m < 3) {
        ushort8v o0, o1;
        o0[0] = f2b(p[0].x); o0[1] = f2b(p[0].y); o0[2] = f2b(p[0].z); o0[3] = f2b(p[0].w);
        o0[4] = f2b(p[1].x); o0[5] = f2b(p[1].y); o0[6] = f2b(p[1].z); o0[7] = f2b(p[1].w);
        o1[0] = f2b(p[2].x); o1[1] = f2b(p[2].y); o1[2] = f2b(p[2].z); o1[3] = f2b(p[2].w);
        o1[4] = f2b(p[3].x); o1[5] = f2b(p[3].y); o1[6] = f2b(p[3].z); o1[7] = f2b(p[3].w);
        *(ushort8v*)&Ob[(size_t)grow * 128 + col] = o0;
        *(ushort8v*)&Ob[(size_t)grow * 128 + col + 8] = o1;
      } else {
#pragma unroll
        for (int j = 0; j < 4; ++j)
          *(float4*)&S[(size_t)grow * 128 + col + j * 4] = p[j];
      }
    }
  }
}

// ---------------- edge aggregation + residual + relu ----------------
// h[i] = relu( S[i] + sum_j sigmoid(K[i]+Q[j]) * V[j] )
// One node per wave; 8 edge slots x 8 lanes x 16ch (2x gather MLP vs 4x16);
// packed bf16 unpack (1 VALU op per channel pair); exp2+rcp sigmoid.

__global__ __launch_bounds__(256) void edge_agg_kernel(
    const unsigned short* __restrict__ Kb, const unsigned short* __restrict__ Qb,
    const unsigned short* __restrict__ Vb, const float* __restrict__ S,
    const int* __restrict__ row_ptr, const int* __restrict__ es,
    unsigned short* __restrict__ Hb, int n) {
  int wid = threadIdx.x >> 6;
  int lane = threadIdx.x & 63;
  int node = blockIdx.x * 4 + wid;
  if (node >= n) return;
  int slot = lane >> 3;      // edge slot 0..7
  int l8 = lane & 7;         // channels l8*16 .. l8*16+15
  int chb = l8 * 16;

  uint4 k0 = *(const uint4*)&Kb[(size_t)node * 128 + chb];
  uint4 k1 = *(const uint4*)&Kb[(size_t)node * 128 + chb + 8];
  float kcn[16];
#pragma unroll
  for (int p = 0; p < 4; ++p) {
    unsigned int u0 = ((const unsigned int*)&k0)[p];
    unsigned int u1 = ((const unsigned int*)&k1)[p];
    kcn[2 * p]     = blo(u0) * (-LOG2E);
    kcn[2 * p + 1] = bhi(u0) * (-LOG2E);
    kcn[8 + 2 * p]     = blo(u1) * (-LOG2E);
    kcn[8 + 2 * p + 1] = bhi(u1) * (-LOG2E);
  }

  float acc[16];
#pragma unroll
  for (int i = 0; i < 16; ++i) acc[i] = 0.0f;

  int e0 = row_ptr[node], e1 = row_ptr[node + 1];
  int e = e0 + slot;
  int j = (e < e1) ? es[e] : -1;
  while (j >= 0) {
    int en = e + 8;
    int jn = (en < e1) ? es[en] : -1;
    uint4 q0 = *(const uint4*)&Qb[(size_t)j * 128 + chb];
    uint4 q1 = *(const uint4*)&Qb[(size_t)j * 128 + chb + 8];
    uint4 v0 = *(const uint4*)&Vb[(size_t)j * 128 + chb];
    uint4 v1 = *(const uint4*)&Vb[(size_t)j * 128 + chb + 8];
#pragma unroll
    for (int p = 0; p < 4; ++p) {
      unsigned int qu0 = ((const unsigned int*)&q0)[p];
      unsigned int qu1 = ((const unsigned int*)&q1)[p];
      unsigned int vu0 = ((const unsigned int*)&v0)[p];
      unsigned int vu1 = ((const unsigned int*)&v1)[p];
      {
        float ex = __builtin_amdgcn_exp2f(fmaf(blo(qu0), -LOG2E, kcn[2 * p]));
        acc[2 * p] = fmaf(blo(vu0), __builtin_amdgcn_rcpf(1.0f + ex), acc[2 * p]);
      }
      {
        float ex = __builtin_amdgcn_exp2f(fmaf(bhi(qu0), -LOG2E, kcn[2 * p + 1]));
        acc[2 * p + 1] = fmaf(bhi(vu0), __builtin_amdgcn_rcpf(1.0f + ex), acc[2 * p + 1]);
      }
      {
        float ex = __builtin_amdgcn_exp2f(fmaf(blo(qu1), -LOG2E, kcn[8 + 2 * p]));
        acc[8 + 2 * p] = fmaf(blo(vu1), __builtin_amdgcn_rcpf(1.0f + ex), acc[8 + 2 * p]);
      }
      {
        float ex = __builtin_amdgcn_exp2f(fmaf(bhi(qu1), -LOG2E, kcn[8 + 2 * p + 1]));
        acc[8 + 2 * p + 1] = fmaf(bhi(vu1), __builtin_amdgcn_rcpf(1.0f + ex), acc[8 + 2 * p + 1]);
      }
    }
    e = en; j = jn;
  }

  // combine 8 edge slots
#pragma unroll
  for (int i = 0; i < 16; ++i) {
    acc[i] += __shfl_xor(acc[i], 8);
    acc[i] += __shfl_xor(acc[i], 16);
    acc[i] += __shfl_xor(acc[i], 32);
  }

  if (slot == 0) {
    ushort8v o0, o1;
#pragma unroll
    for (int q = 0; q < 4; ++q) {
      float4 sv = *(const float4*)&S[(size_t)node * 128 + chb + q * 4];
      float r0 = fmaxf(acc[q * 4 + 0] + sv.x, 0.f);
      float r1 = fmaxf(acc[q * 4 + 1] + sv.y, 0.f);
      float r2 = fmaxf(acc[q * 4 + 2] + sv.z, 0.f);
      float r3 = fmaxf(acc[q * 4 + 3] + sv.w, 0.f);
      if (q < 2) {
        o0[q * 4 + 0] = f2b(r0); o0[q * 4 + 1] = f2b(r1);
        o0[q * 4 + 2] = f2b(r2); o0[q * 4 + 3] = f2b(r3);
      } else {
        o1[(q - 2) * 4 + 0] = f2b(r0); o1[(q - 2) * 4 + 1] = f2b(r1);
        o1[(q - 2) * 4 + 2] = f2b(r2); o1[(q - 2) * 4 + 3] = f2b(r3);
      }
    }
    *(ushort8v*)&Hb[(size_t)node * 128 + chb] = o0;
    *(ushort8v*)&Hb[(size_t)node * 128 + chb + 8] = o1;
  }
}

// ---------------- mean pool + FC (graph bounds via binary search) ----------

__device__ __forceinline__ int lb_batch(const int* __restrict__ batch, int n, int key) {
  int lo = 0, hi = n;
  while (lo < hi) {
    int mid = (lo + hi) >> 1;
    if (batch[mid] < key) lo = mid + 1; else hi = mid;
  }
  return lo;
}

// 16 slices per graph -> partial[slice][g][128], no atomics.
__global__ __launch_bounds__(256) void pool_sum_kernel(const unsigned short* __restrict__ Hb,
                                                       const int* __restrict__ batch,
                                                       float* __restrict__ partial, int n) {
  __shared__ float red[8 * 128];
  int g = blockIdx.x >> 4;
  int slice = blockIdx.x & 15;
  int t = threadIdx.x;
  int grp = t >> 5;        // 0..7: node stripe
  int cq = t & 31;         // channel quad: ch cq*4..cq*4+3
  int s = lb_batch(batch, n, g), e = lb_batch(batch, n, g + 1);
  int cnt = e - s;
  int per = (cnt + 15) >> 4;
  int ss = s + slice * per;
  int ee = ss + per; if (ee > e) ee = e;

  float4 acc = make_float4(0.f, 0.f, 0.f, 0.f);
  for (int nd = ss + grp; nd < ee; nd += 8) {
    uint2 u = *(const uint2*)&Hb[(size_t)nd * 128 + cq * 4];
    acc.x += blo(u.x); acc.y += bhi(u.x);
    acc.z += blo(u.y); acc.w += bhi(u.y);
  }
  *(float4*)&red[grp * 128 + cq * 4] = acc;
  __syncthreads();
  if (t < 128) {
    float tot = 0.f;
#pragma unroll
    for (int g8 = 0; g8 < 8; ++g8) tot += red[g8 * 128 + t];
    partial[(size_t)slice * 8192 + g * 128 + t] = tot;
  }
}

__global__ __launch_bounds__(128) void fc_kernel(const float* __restrict__ partial,
                                                 const int* __restrict__ batch,
                                                 const float* __restrict__ fcW,
                                                 const float* __restrict__ fcb,
                                                 float* __restrict__ out, int n) {
  __shared__ float p[128];
  int g = blockIdx.x;
  int t = threadIdx.x;
  int cnt = lb_batch(batch, n, g + 1) - lb_batch(batch, n, g);
  float inv = 1.0f / (float)((cnt > 0) ? cnt : 1);
  float tot = 0.f;
#pragma unroll
  for (int s = 0; s < 16; ++s) tot += partial[(size_t)s * 8192 + g * 128 + t];
  p[t] = tot * inv;
  __syncthreads();
  if (t < 10) {
    float s = fcb[t];
    for (int c = 0; c < 128; ++c) s += p[c] * fcW[c * 10 + t];
    out[g * 10 + t] = s;
  }
}

// ---------------------------------------------------------------------------

extern "C" void kernel_launch(void* const* d_in, const int* in_sizes, int n_in,
                              void* d_out, int out_size, void* d_ws, size_t ws_size,
                              hipStream_t stream) {
  const float* x   = (const float*)d_in[0];
  const int* eidx  = (const int*)d_in[1];
  const int* batch = (const int*)d_in[2];
  const float* Wk1 = (const float*)d_in[3];  const float* bk1 = (const float*)d_in[4];
  const float* Wq1 = (const float*)d_in[5];  const float* bq1 = (const float*)d_in[6];
  const float* Wv1 = (const float*)d_in[7];  const float* bv1 = (const float*)d_in[8];
  const float* Ws1 = (const float*)d_in[9];  const float* bs1 = (const float*)d_in[10];
  const float* b1  = (const float*)d_in[11];
  const float* Wk2 = (const float*)d_in[12]; const float* bk2 = (const float*)d_in[13];
  const float* Wq2 = (const float*)d_in[14]; const float* bq2 = (const float*)d_in[15];
  const float* Wv2 = (const float*)d_in[16]; const float* bv2 = (const float*)d_in[17];
  const float* Ws2 = (const float*)d_in[18]; const float* bs2 = (const float*)d_in[19];
  const float* b2  = (const float*)d_in[20];
  const float* fcW = (const float*)d_in[21]; const float* fcb = (const float*)d_in[22];
  float* out = (float*)d_out;

  const int N = in_sizes[0] / 128;   // 50000
  const int E = in_sizes[1] / 2;     // 800000
  const int* src = eidx;
  const int* dst = eidx + E;

  // ---- workspace carve ----
  char* w = (char*)d_ws;
  size_t off = 0;
  auto carve = [&](size_t bytes) -> void* {
    void* p = w + off;
    off += (bytes + 255) & ~size_t(255);
    return p;
  };
  const size_t featB16 = (size_t)N * 128 * 2;
  const size_t featB32 = (size_t)N * 128 * 4;
  unsigned short* Xb = (unsigned short*)carve(featB16);
  unsigned short* Kb = (unsigned short*)carve(featB16);
  unsigned short* Qb = (unsigned short*)carve(featB16);
  unsigned short* Vb = (unsigned short*)carve(featB16);
  unsigned short* Hb = (unsigned short*)carve(featB16);
  float* S  = (float*)carve(featB32);
  unsigned short* WT = (unsigned short*)carve(2 * 4 * 128 * 128 * 2);
  float* bcat = (float*)carve(1024 * 4);
  int* cnt      = (int*)carve(((size_t)N + 4) * 4);
  int* row_ptr  = (int*)carve((size_t)(N + 1) * 4);
  int* cursor   = (int*)carve((size_t)N * 4);
  int* tmp_excl = (int*)carve((size_t)N * 4);
  int* bsum     = (int*)carve(256 * 4);
  int* es       = (int*)carve((size_t)E * 4);
  float* partial = (float*)carve((size_t)16 * 64 * 128 * 4);
  (void)ws_size; (void)n_in; (void)out_size;

  // ---- prep (x->bf16, weights, biases, zero cnt) then CSR build ----
  int nconvb = (N * 32 + 255) / 256;
  int ncnt4 = (N + 3) / 4;
  int nzerob = (ncnt4 + 255) / 256;
  prep_kernel<<<nconvb + nzerob + 512 + 4, 256, 0, stream>>>(
      x, Xb, N * 32,
      Wk1, Wq1, Wv1, Ws1, Wk2, Wq2, Wv2, Ws2, WT,
      bk1, bq1, bv1, bs1, b1, bk2, bq2, bv2, bs2, b2, bcat,
      cnt, ncnt4, nconvb, nzerob);

  int nb512 = (N + 511) / 512;
  hist_kernel<<<(E + 255) / 256, 256, 0, stream>>>(dst, cnt, E);
  scan1_kernel<<<nb512, 256, 0, stream>>>(cnt, tmp_excl, bsum, N);
  finalize_rp_kernel<<<(N + 255) / 256, 256, 0, stream>>>(tmp_excl, bsum, row_ptr,
                                                          cursor, N, E, nb512);
  scatter_kernel<<<(E + 255) / 256, 256, 0, stream>>>(src, dst, cursor, es, E);

  dim3 ggrid((N + 127) / 128, 4);

  // ---- layer 1 ----
  gemm_mfma_kernel<<<ggrid, 256, 0, stream>>>(Xb, WT, bcat, Kb, Qb, Vb, S, N);
  edge_agg_kernel<<<(N + 3) / 4, 256, 0, stream>>>(Kb, Qb, Vb, S, row_ptr, es, Hb, N);

  // ---- layer 2 ----
  gemm_mfma_kernel<<<ggrid, 256, 0, stream>>>(Hb, WT + 65536, bcat + 512,
                                              Kb, Qb, Vb, S, N);
  edge_agg_kernel<<<(N + 3) / 4, 256, 0, stream>>>(Kb, Qb, Vb, S, row_ptr, es, Hb, N);

  // ---- pool + fc ----
  pool_sum_kernel<<<1024, 256, 0, stream>>>(Hb, batch, partial, N);
  fc_kernel<<<64, 128, 0, stream>>>(partial, batch, fcW, fcb, out, N);
}